// Round 3
// baseline (278.703 us; speedup 1.0000x reference)
//
#include <hip/hip_runtime.h>
#include <limits.h>

// Problem constants (fixed by the reference: LATTICE=(4096,4096), N_CLUSTERS=262144)
#define N_SITES   (4096 * 4096)      // 16,777,216
#define N_LABELS  262144
#define NWORDS    (N_SITES / 32)     // 524,288 bitmap words
#define WPC       256                // words per chunk
#define NCHUNKS   (NWORDS / WPC)     // 2048

// k_first geometry: persistent blocks sweep the array in contiguous segments,
// low indices first, so the early-out filter sees a populated first_idx table
// for all but the first window. 2048 blocks x 256 thr = 8 waves/SIMD (100%
// occupancy at 8 VGPR); 2-way ILP gives 2 label loads + 8 probes in flight.
#define FIRST_BLOCKS 2048
#define FIRST_TPB    256

// ---------------- kernel 1: init first_idx + bitmap ----------------
__global__ void k_init(int* __restrict__ first_idx, unsigned* __restrict__ bitmap) {
    int t = blockIdx.x * blockDim.x + threadIdx.x;
    if (t < NWORDS)   bitmap[t] = 0u;
    if (t < N_LABELS) first_idx[t] = INT_MAX;
}

// ---------------- kernel 2: first occurrence per label (segment_min) ----------------
// Early-out before atomic: first_idx[l] is monotone decreasing from INT_MAX and
// every stored value was legitimately written, so "skip if current <= my index"
// is correct even under stale reads (staleness only causes a redundant,
// harmless atomic). The pair (t, t+STRIDE) both lie in the current low->high
// sweep window, so the filter stays effective after the first window.
__global__ void k_first(const int4* __restrict__ lab4, int* __restrict__ first_idx, int n4) {
    const int STRIDE = FIRST_BLOCKS * FIRST_TPB;   // 524,288 int4
    int base = blockIdx.x * blockDim.x + threadIdx.x;
    // n4 = 8 * STRIDE exactly; unroll 2 -> 4 outer iterations.
    for (int t0 = base; t0 < n4; t0 += 2 * STRIDE) {
        int t1 = t0 + STRIDE;
        int4 La = lab4[t0];
        int4 Lb = lab4[t1];
        int a = t0 * 4, b = t1 * 4;
        // issue all 8 probes (independent scattered loads) before atomics
        int pax = first_idx[La.x], pay = first_idx[La.y];
        int paz = first_idx[La.z], paw = first_idx[La.w];
        int pbx = first_idx[Lb.x], pby = first_idx[Lb.y];
        int pbz = first_idx[Lb.z], pbw = first_idx[Lb.w];
        if (a     < pax) atomicMin(&first_idx[La.x], a);
        if (a + 1 < pay) atomicMin(&first_idx[La.y], a + 1);
        if (a + 2 < paz) atomicMin(&first_idx[La.z], a + 2);
        if (a + 3 < paw) atomicMin(&first_idx[La.w], a + 3);
        if (b     < pbx) atomicMin(&first_idx[Lb.x], b);
        if (b + 1 < pby) atomicMin(&first_idx[Lb.y], b + 1);
        if (b + 2 < pbz) atomicMin(&first_idx[Lb.z], b + 2);
        if (b + 3 < pbw) atomicMin(&first_idx[Lb.w], b + 3);
    }
}

// ---------------- kernel 3: scatter seed bits into occupancy bitmap ----------------
__global__ void k_scatter(const int* __restrict__ first_idx, unsigned* __restrict__ bitmap) {
    int l = blockIdx.x * blockDim.x + threadIdx.x;
    if (l >= N_LABELS) return;
    int fi = first_idx[l];
    if (fi != INT_MAX) atomicOr(&bitmap[fi >> 5], 1u << (fi & 31));
}

// ---------------- kernel 4: per-chunk popcount sums ----------------
__global__ void k_chunk_sums(const unsigned* __restrict__ bitmap, int* __restrict__ chunkSums) {
    __shared__ int waveSums[4];
    int w  = blockIdx.x * WPC + threadIdx.x;
    int pc = __popc(bitmap[w]);
    #pragma unroll
    for (int off = 32; off; off >>= 1) pc += __shfl_down(pc, off);
    if ((threadIdx.x & 63) == 0) waveSums[threadIdx.x >> 6] = pc;
    __syncthreads();
    if (threadIdx.x == 0)
        chunkSums[blockIdx.x] = waveSums[0] + waveSums[1] + waveSums[2] + waveSums[3];
}

// ---------------- kernel 5: single-block exclusive scan of chunk sums ----------------
__global__ void k_scan(int* __restrict__ data, int n) {  // n multiple of 256
    __shared__ int lds[256];
    int tid = threadIdx.x;
    int carry = 0;
    for (int base = 0; base < n; base += 256) {
        int v = data[base + tid];
        lds[tid] = v;
        __syncthreads();
        for (int off = 1; off < 256; off <<= 1) {
            int add = (tid >= off) ? lds[tid - off] : 0;
            __syncthreads();
            lds[tid] += add;
            __syncthreads();
        }
        int incl  = lds[tid];
        int total = lds[255];
        __syncthreads();                  // protect lds before next tile overwrite
        data[base + tid] = incl - v + carry;   // exclusive prefix
        carry += total;
    }
}

// ---------------- kernel 6: per-word global exclusive prefix ----------------
__global__ void k_word_prefix(const unsigned* __restrict__ bitmap,
                              const int* __restrict__ chunkPref,
                              int* __restrict__ wordPrefix) {
    __shared__ int lds[256];
    int tid = threadIdx.x;
    int w   = blockIdx.x * WPC + tid;
    int pc  = __popc(bitmap[w]);
    lds[tid] = pc;
    __syncthreads();
    for (int off = 1; off < 256; off <<= 1) {
        int add = (tid >= off) ? lds[tid - off] : 0;
        __syncthreads();
        lds[tid] += add;
        __syncthreads();
    }
    wordPrefix[w] = chunkPref[blockIdx.x] + lds[tid] - pc;  // exclusive
}

// ---------------- kernel 7: rank -> coin -> flip decision per label ----------------
__global__ void k_rank_flip(const int* __restrict__ first_idx,
                            const unsigned* __restrict__ bitmap,
                            const int* __restrict__ wordPrefix,
                            const float* __restrict__ coins,
                            unsigned char* __restrict__ flip) {
    int l = blockIdx.x * blockDim.x + threadIdx.x;
    if (l >= N_LABELS) return;
    int fi = first_idx[l];
    if (fi == INT_MAX) return;           // label absent; flip[l] never read
    int w = fi >> 5;
    unsigned mask = (1u << (fi & 31)) - 1u;
    int rank = wordPrefix[w] + __popc(bitmap[w] & mask);
    flip[l] = (coins[rank] >= 0.5f) ? 1 : 0;
}

// ---------------- kernel 8: apply flips ----------------
__global__ void k_out(const int4* __restrict__ lab4, const float4* __restrict__ sp4,
                      const unsigned char* __restrict__ flip,
                      float4* __restrict__ out4, int n4) {
    int t = blockIdx.x * blockDim.x + threadIdx.x;
    if (t >= n4) return;
    int4   L = lab4[t];
    float4 s = sp4[t];
    float4 o;
    o.x = flip[L.x] ? -s.x : s.x;
    o.y = flip[L.y] ? -s.y : s.y;
    o.z = flip[L.z] ? -s.z : s.z;
    o.w = flip[L.w] ? -s.w : s.w;
    out4[t] = o;
}

extern "C" void kernel_launch(void* const* d_in, const int* in_sizes, int n_in,
                              void* d_out, int out_size, void* d_ws, size_t ws_size,
                              hipStream_t stream) {
    const float* spins  = (const float*)d_in[0];
    const int*   labels = (const int*)d_in[1];
    const float* coins  = (const float*)d_in[2];
    float*       out    = (float*)d_out;

    // workspace layout (total ~5.3 MB)
    char* ws = (char*)d_ws;
    int*           first_idx  = (int*)ws;                              // 1 MB
    unsigned*      bitmap     = (unsigned*)(ws + (1u << 20));          // 2 MB
    int*           wordPrefix = (int*)(ws + 3u * (1u << 20));          // 2 MB
    int*           chunkSums  = (int*)(ws + 5u * (1u << 20));          // 8 KB
    unsigned char* flip       = (unsigned char*)(ws + 5u*(1u<<20) + (1u<<14)); // 256 KB

    const int n  = N_SITES;
    const int n4 = n / 4;

    k_init<<<(NWORDS + 255) / 256, 256, 0, stream>>>(first_idx, bitmap);
    k_first<<<FIRST_BLOCKS, FIRST_TPB, 0, stream>>>((const int4*)labels, first_idx, n4);
    k_scatter<<<N_LABELS / 256, 256, 0, stream>>>(first_idx, bitmap);
    k_chunk_sums<<<NCHUNKS, WPC, 0, stream>>>(bitmap, chunkSums);
    k_scan<<<1, 256, 0, stream>>>(chunkSums, NCHUNKS);
    k_word_prefix<<<NCHUNKS, WPC, 0, stream>>>(bitmap, chunkSums, wordPrefix);
    k_rank_flip<<<N_LABELS / 256, 256, 0, stream>>>(first_idx, bitmap, wordPrefix, coins, flip);
    k_out<<<n4 / 256, 256, 0, stream>>>((const int4*)labels, (const float4*)spins, flip,
                                        (float4*)out, n4);
}

// Round 4
// 243.923 us; speedup vs baseline: 1.1426x; 1.1426x over previous
//
#include <hip/hip_runtime.h>
#include <limits.h>

// Problem constants (fixed by the reference: LATTICE=(4096,4096), N_CLUSTERS=262144)
#define N_SITES   (4096 * 4096)      // 16,777,216
#define N_LABELS  262144
#define NWORDS    (N_SITES / 32)     // 524,288 bitmap words
#define NSEENW    (N_LABELS / 32)    // 8,192 seen/flip bitmap words (32 KB)
#define WPC       256                // words per chunk
#define NCHUNKS   (NWORDS / WPC)     // 2048

// k_first geometry (R2's best): 1024 blocks x 256 thr sweep the array in 16
// contiguous segments, low indices first.
#define FIRST_BLOCKS 1024
#define FIRST_TPB    256

// ---------------- kernel 1: init tables ----------------
__global__ void k_init(int* __restrict__ first_idx, unsigned* __restrict__ bitmap,
                       unsigned* __restrict__ seen, unsigned* __restrict__ flipbits) {
    int t = blockIdx.x * blockDim.x + threadIdx.x;
    if (t < NWORDS)   bitmap[t] = 0u;
    if (t < N_LABELS) first_idx[t] = INT_MAX;
    if (t < NSEENW) { seen[t] = 0u; flipbits[t] = 0u; }
}

// ---------------- kernel 2: first occurrence per label (segment_min) ----------------
// Segment 0 (sites [0, 1M)): value-filtered atomicMin + set 'seen' bit.
// Segments 1..15: probe the 32 KB read-only 'seen' bitmap (L1-resident per CU);
// only clear bits (rare: labels absent from segment 0, or stale reads) fall
// through to the exact atomicMin path.
// Exactness: a set bit implies a segment-0 occurrence at a strictly lower index
// whose atomicMin completes before kernel end, so skipping is always correct.
// Stale-clear reads merely cause redundant exact atomics. Bits are never set
// outside segment 0 (same-segment setting would race the raster-order min).
__global__ void k_first(const int4* __restrict__ lab4, int* __restrict__ first_idx,
                        unsigned* __restrict__ seen, int n4) {
    const int SEG = FIRST_BLOCKS * FIRST_TPB;   // 262,144 int4 = 1,048,576 sites
    int base = blockIdx.x * blockDim.x + threadIdx.x;
    // ---- segment 0 ----
    {
        int4 L = lab4[base];
        int b  = base * 4;
        if (b     < first_idx[L.x]) { atomicMin(&first_idx[L.x], b);     atomicOr(&seen[L.x >> 5], 1u << (L.x & 31)); }
        if (b + 1 < first_idx[L.y]) { atomicMin(&first_idx[L.y], b + 1); atomicOr(&seen[L.y >> 5], 1u << (L.y & 31)); }
        if (b + 2 < first_idx[L.z]) { atomicMin(&first_idx[L.z], b + 2); atomicOr(&seen[L.z >> 5], 1u << (L.z & 31)); }
        if (b + 3 < first_idx[L.w]) { atomicMin(&first_idx[L.w], b + 3); atomicOr(&seen[L.w >> 5], 1u << (L.w & 31)); }
    }
    // ---- segments 1..15 ----
    for (int t = base + SEG; t < n4; t += SEG) {
        int4 L = lab4[t];
        int b  = t * 4;
        unsigned sx = seen[L.x >> 5], sy = seen[L.y >> 5];
        unsigned sz = seen[L.z >> 5], sw = seen[L.w >> 5];
        if (!((sx >> (L.x & 31)) & 1u)) { if (b     < first_idx[L.x]) atomicMin(&first_idx[L.x], b);     }
        if (!((sy >> (L.y & 31)) & 1u)) { if (b + 1 < first_idx[L.y]) atomicMin(&first_idx[L.y], b + 1); }
        if (!((sz >> (L.z & 31)) & 1u)) { if (b + 2 < first_idx[L.z]) atomicMin(&first_idx[L.z], b + 2); }
        if (!((sw >> (L.w & 31)) & 1u)) { if (b + 3 < first_idx[L.w]) atomicMin(&first_idx[L.w], b + 3); }
    }
}

// ---------------- kernel 3: scatter seed bits into occupancy bitmap ----------------
__global__ void k_scatter(const int* __restrict__ first_idx, unsigned* __restrict__ bitmap) {
    int l = blockIdx.x * blockDim.x + threadIdx.x;
    if (l >= N_LABELS) return;
    int fi = first_idx[l];
    if (fi != INT_MAX) atomicOr(&bitmap[fi >> 5], 1u << (fi & 31));
}

// ---------------- kernel 4: per-chunk popcount sums ----------------
__global__ void k_chunk_sums(const unsigned* __restrict__ bitmap, int* __restrict__ chunkSums) {
    __shared__ int waveSums[4];
    int w  = blockIdx.x * WPC + threadIdx.x;
    int pc = __popc(bitmap[w]);
    #pragma unroll
    for (int off = 32; off; off >>= 1) pc += __shfl_down(pc, off);
    if ((threadIdx.x & 63) == 0) waveSums[threadIdx.x >> 6] = pc;
    __syncthreads();
    if (threadIdx.x == 0)
        chunkSums[blockIdx.x] = waveSums[0] + waveSums[1] + waveSums[2] + waveSums[3];
}

// ---------------- kernel 5: single-block exclusive scan of chunk sums ----------------
__global__ void k_scan(int* __restrict__ data, int n) {  // n multiple of 256
    __shared__ int lds[256];
    int tid = threadIdx.x;
    int carry = 0;
    for (int base = 0; base < n; base += 256) {
        int v = data[base + tid];
        lds[tid] = v;
        __syncthreads();
        for (int off = 1; off < 256; off <<= 1) {
            int add = (tid >= off) ? lds[tid - off] : 0;
            __syncthreads();
            lds[tid] += add;
            __syncthreads();
        }
        int incl  = lds[tid];
        int total = lds[255];
        __syncthreads();                  // protect lds before next tile overwrite
        data[base + tid] = incl - v + carry;   // exclusive prefix
        carry += total;
    }
}

// ---------------- kernel 6: per-word global exclusive prefix ----------------
__global__ void k_word_prefix(const unsigned* __restrict__ bitmap,
                              const int* __restrict__ chunkPref,
                              int* __restrict__ wordPrefix) {
    __shared__ int lds[256];
    int tid = threadIdx.x;
    int w   = blockIdx.x * WPC + tid;
    int pc  = __popc(bitmap[w]);
    lds[tid] = pc;
    __syncthreads();
    for (int off = 1; off < 256; off <<= 1) {
        int add = (tid >= off) ? lds[tid - off] : 0;
        __syncthreads();
        lds[tid] += add;
        __syncthreads();
    }
    wordPrefix[w] = chunkPref[blockIdx.x] + lds[tid] - pc;  // exclusive
}

// ---------------- kernel 7: rank -> coin -> flip bit per label ----------------
__global__ void k_rank_flip(const int* __restrict__ first_idx,
                            const unsigned* __restrict__ bitmap,
                            const int* __restrict__ wordPrefix,
                            const float* __restrict__ coins,
                            unsigned* __restrict__ flipbits) {
    int l = blockIdx.x * blockDim.x + threadIdx.x;
    if (l >= N_LABELS) return;
    int fi = first_idx[l];
    if (fi == INT_MAX) return;           // label absent; its flip bit never read
    int w = fi >> 5;
    unsigned mask = (1u << (fi & 31)) - 1u;
    int rank = wordPrefix[w] + __popc(bitmap[w] & mask);
    if (coins[rank] >= 0.5f) atomicOr(&flipbits[l >> 5], 1u << (l & 31));
}

// ---------------- kernel 8: apply flips (branchless sign-bit XOR) ----------------
__global__ void k_out(const int4* __restrict__ lab4, const float4* __restrict__ sp4,
                      const unsigned* __restrict__ flipbits,
                      float4* __restrict__ out4, int n4) {
    int t = blockIdx.x * blockDim.x + threadIdx.x;
    if (t >= n4) return;
    int4   L = lab4[t];
    float4 s = sp4[t];
    unsigned bx = (flipbits[L.x >> 5] >> (L.x & 31)) & 1u;
    unsigned by = (flipbits[L.y >> 5] >> (L.y & 31)) & 1u;
    unsigned bz = (flipbits[L.z >> 5] >> (L.z & 31)) & 1u;
    unsigned bw = (flipbits[L.w >> 5] >> (L.w & 31)) & 1u;
    float4 o;
    o.x = __uint_as_float(__float_as_uint(s.x) ^ (bx << 31));
    o.y = __uint_as_float(__float_as_uint(s.y) ^ (by << 31));
    o.z = __uint_as_float(__float_as_uint(s.z) ^ (bz << 31));
    o.w = __uint_as_float(__float_as_uint(s.w) ^ (bw << 31));
    out4[t] = o;
}

extern "C" void kernel_launch(void* const* d_in, const int* in_sizes, int n_in,
                              void* d_out, int out_size, void* d_ws, size_t ws_size,
                              hipStream_t stream) {
    const float* spins  = (const float*)d_in[0];
    const int*   labels = (const int*)d_in[1];
    const float* coins  = (const float*)d_in[2];
    float*       out    = (float*)d_out;

    // workspace layout (~5.1 MB total)
    char* ws = (char*)d_ws;
    int*      first_idx  = (int*)ws;                                   // 1 MB
    unsigned* bitmap     = (unsigned*)(ws + (1u << 20));               // 2 MB
    int*      wordPrefix = (int*)(ws + 3u * (1u << 20));               // 2 MB
    int*      chunkSums  = (int*)(ws + 5u * (1u << 20));               // 8 KB
    unsigned* seen       = (unsigned*)(ws + 5u*(1u<<20) + (1u<<14));   // 32 KB
    unsigned* flipbits   = (unsigned*)(ws + 5u*(1u<<20) + (1u<<14) + (1u<<15)); // 32 KB

    const int n  = N_SITES;
    const int n4 = n / 4;

    k_init<<<(NWORDS + 255) / 256, 256, 0, stream>>>(first_idx, bitmap, seen, flipbits);
    k_first<<<FIRST_BLOCKS, FIRST_TPB, 0, stream>>>((const int4*)labels, first_idx, seen, n4);
    k_scatter<<<N_LABELS / 256, 256, 0, stream>>>(first_idx, bitmap);
    k_chunk_sums<<<NCHUNKS, WPC, 0, stream>>>(bitmap, chunkSums);
    k_scan<<<1, 256, 0, stream>>>(chunkSums, NCHUNKS);
    k_word_prefix<<<NCHUNKS, WPC, 0, stream>>>(bitmap, chunkSums, wordPrefix);
    k_rank_flip<<<N_LABELS / 256, 256, 0, stream>>>(first_idx, bitmap, wordPrefix, coins, flipbits);
    k_out<<<n4 / 256, 256, 0, stream>>>((const int4*)labels, (const float4*)spins, flipbits,
                                        (float4*)out, n4);
}

// Round 5
// 177.571 us; speedup vs baseline: 1.5695x; 1.3737x over previous
//
#include <hip/hip_runtime.h>
#include <limits.h>

// Problem constants (fixed by the reference: LATTICE=(4096,4096), N_CLUSTERS=262144)
#define N_SITES   (4096 * 4096)      // 16,777,216
#define N_LABELS  262144
#define NWORDS    (N_SITES / 32)     // 524,288 bitmap words
#define NSEENW    (N_LABELS / 32)    // 8,192 seen/flip bitmap words (32 KB)
#define WPC       256                // words per chunk
#define NCHUNKS   (NWORDS / WPC)     // 2048

// Seed pass geometry: 512 blocks x 256 thr sweep sites [0, 1M) in 2 low-first
// windows, so the value filter sees a mostly-populated table in window 1.
#define SEED_SITES  (1 << 20)        // 1,048,576 sites seeded
#define SEED_BLOCKS 512
#define SEED_TPB    256

// ---------------- kernel 1: init tables ----------------
__global__ void k_init(int* __restrict__ first_idx, unsigned* __restrict__ bitmap,
                       unsigned* __restrict__ flipbits) {
    int t = blockIdx.x * blockDim.x + threadIdx.x;
    if (t < NWORDS)   bitmap[t] = 0u;
    if (t < N_LABELS) first_idx[t] = INT_MAX;
    if (t < NSEENW)   flipbits[t] = 0u;
}

// ---------------- kernel 2a: seed pass over sites [0, 1M) ----------------
// Value-filtered atomicMin (filter correct under stale reads: values only
// decrease and every stored value was legitimately written; a stale-high read
// merely causes a redundant exact atomic).
__global__ void k_seed(const int4* __restrict__ lab4, int* __restrict__ first_idx) {
    const int STRIDE = SEED_BLOCKS * SEED_TPB;      // 131,072 int4 = 524,288 sites
    int base = blockIdx.x * blockDim.x + threadIdx.x;
    for (int t = base; t < SEED_SITES / 4; t += STRIDE) {   // 2 iterations
        int4 L = lab4[t];
        int b  = t * 4;
        if (b     < first_idx[L.x]) atomicMin(&first_idx[L.x], b);
        if (b + 1 < first_idx[L.y]) atomicMin(&first_idx[L.y], b + 1);
        if (b + 2 < first_idx[L.z]) atomicMin(&first_idx[L.z], b + 2);
        if (b + 3 < first_idx[L.w]) atomicMin(&first_idx[L.w], b + 3);
    }
}

// ---------------- kernel 2b: build 32 KB 'seen' bitmap from first_idx ----------------
// One thread per label; wave ballot composes 64 labels -> 2 words. No atomics.
__global__ void k_seen(const int* __restrict__ first_idx, unsigned* __restrict__ seen) {
    int l = blockIdx.x * blockDim.x + threadIdx.x;       // N_LABELS threads
    unsigned long long m = __ballot(first_idx[l] != INT_MAX);
    int lane = threadIdx.x & 63;
    if (lane == 0)       seen[l >> 5] = (unsigned)m;
    else if (lane == 32) seen[l >> 5] = (unsigned)(m >> 32);
}

// ---------------- kernel 2c: completion pass over ALL sites (flat, no loop) ----------------
// Probe the read-only seen bitmap; a set bit implies first_idx[l] was written
// with an index < 2^20 by the (completed) seed pass, so skipping is exact.
// Clear bits (~2% of labels; ~300K sites) take the exact filtered-atomic path.
__global__ void k_first_flat(const int4* __restrict__ lab4, int* __restrict__ first_idx,
                             const unsigned* __restrict__ seen, int n4) {
    int t = blockIdx.x * blockDim.x + threadIdx.x;
    if (t >= n4) return;
    int4 L = lab4[t];
    int b  = t * 4;
    unsigned sx = seen[L.x >> 5], sy = seen[L.y >> 5];
    unsigned sz = seen[L.z >> 5], sw = seen[L.w >> 5];
    if (!((sx >> (L.x & 31)) & 1u)) { if (b     < first_idx[L.x]) atomicMin(&first_idx[L.x], b);     }
    if (!((sy >> (L.y & 31)) & 1u)) { if (b + 1 < first_idx[L.y]) atomicMin(&first_idx[L.y], b + 1); }
    if (!((sz >> (L.z & 31)) & 1u)) { if (b + 2 < first_idx[L.z]) atomicMin(&first_idx[L.z], b + 2); }
    if (!((sw >> (L.w & 31)) & 1u)) { if (b + 3 < first_idx[L.w]) atomicMin(&first_idx[L.w], b + 3); }
}

// ---------------- kernel 3: scatter seed bits into occupancy bitmap ----------------
__global__ void k_scatter(const int* __restrict__ first_idx, unsigned* __restrict__ bitmap) {
    int l = blockIdx.x * blockDim.x + threadIdx.x;
    if (l >= N_LABELS) return;
    int fi = first_idx[l];
    if (fi != INT_MAX) atomicOr(&bitmap[fi >> 5], 1u << (fi & 31));
}

// ---------------- kernel 4: per-chunk popcount sums ----------------
__global__ void k_chunk_sums(const unsigned* __restrict__ bitmap, int* __restrict__ chunkSums) {
    __shared__ int waveSums[4];
    int w  = blockIdx.x * WPC + threadIdx.x;
    int pc = __popc(bitmap[w]);
    #pragma unroll
    for (int off = 32; off; off >>= 1) pc += __shfl_down(pc, off);
    if ((threadIdx.x & 63) == 0) waveSums[threadIdx.x >> 6] = pc;
    __syncthreads();
    if (threadIdx.x == 0)
        chunkSums[blockIdx.x] = waveSums[0] + waveSums[1] + waveSums[2] + waveSums[3];
}

// ---------------- kernel 5: single-block exclusive scan of chunk sums ----------------
__global__ void k_scan(int* __restrict__ data, int n) {  // n multiple of 256
    __shared__ int lds[256];
    int tid = threadIdx.x;
    int carry = 0;
    for (int base = 0; base < n; base += 256) {
        int v = data[base + tid];
        lds[tid] = v;
        __syncthreads();
        for (int off = 1; off < 256; off <<= 1) {
            int add = (tid >= off) ? lds[tid - off] : 0;
            __syncthreads();
            lds[tid] += add;
            __syncthreads();
        }
        int incl  = lds[tid];
        int total = lds[255];
        __syncthreads();                  // protect lds before next tile overwrite
        data[base + tid] = incl - v + carry;   // exclusive prefix
        carry += total;
    }
}

// ---------------- kernel 6: per-word global exclusive prefix ----------------
__global__ void k_word_prefix(const unsigned* __restrict__ bitmap,
                              const int* __restrict__ chunkPref,
                              int* __restrict__ wordPrefix) {
    __shared__ int lds[256];
    int tid = threadIdx.x;
    int w   = blockIdx.x * WPC + tid;
    int pc  = __popc(bitmap[w]);
    lds[tid] = pc;
    __syncthreads();
    for (int off = 1; off < 256; off <<= 1) {
        int add = (tid >= off) ? lds[tid - off] : 0;
        __syncthreads();
        lds[tid] += add;
        __syncthreads();
    }
    wordPrefix[w] = chunkPref[blockIdx.x] + lds[tid] - pc;  // exclusive
}

// ---------------- kernel 7: rank -> coin -> flip bit per label ----------------
__global__ void k_rank_flip(const int* __restrict__ first_idx,
                            const unsigned* __restrict__ bitmap,
                            const int* __restrict__ wordPrefix,
                            const float* __restrict__ coins,
                            unsigned* __restrict__ flipbits) {
    int l = blockIdx.x * blockDim.x + threadIdx.x;
    if (l >= N_LABELS) return;
    int fi = first_idx[l];
    if (fi == INT_MAX) return;           // label absent; its flip bit never read
    int w = fi >> 5;
    unsigned mask = (1u << (fi & 31)) - 1u;
    int rank = wordPrefix[w] + __popc(bitmap[w] & mask);
    if (coins[rank] >= 0.5f) atomicOr(&flipbits[l >> 5], 1u << (l & 31));
}

// ---------------- kernel 8: apply flips (branchless sign-bit XOR) ----------------
__global__ void k_out(const int4* __restrict__ lab4, const float4* __restrict__ sp4,
                      const unsigned* __restrict__ flipbits,
                      float4* __restrict__ out4, int n4) {
    int t = blockIdx.x * blockDim.x + threadIdx.x;
    if (t >= n4) return;
    int4   L = lab4[t];
    float4 s = sp4[t];
    unsigned bx = (flipbits[L.x >> 5] >> (L.x & 31)) & 1u;
    unsigned by = (flipbits[L.y >> 5] >> (L.y & 31)) & 1u;
    unsigned bz = (flipbits[L.z >> 5] >> (L.z & 31)) & 1u;
    unsigned bw = (flipbits[L.w >> 5] >> (L.w & 31)) & 1u;
    float4 o;
    o.x = __uint_as_float(__float_as_uint(s.x) ^ (bx << 31));
    o.y = __uint_as_float(__float_as_uint(s.y) ^ (by << 31));
    o.z = __uint_as_float(__float_as_uint(s.z) ^ (bz << 31));
    o.w = __uint_as_float(__float_as_uint(s.w) ^ (bw << 31));
    out4[t] = o;
}

extern "C" void kernel_launch(void* const* d_in, const int* in_sizes, int n_in,
                              void* d_out, int out_size, void* d_ws, size_t ws_size,
                              hipStream_t stream) {
    const float* spins  = (const float*)d_in[0];
    const int*   labels = (const int*)d_in[1];
    const float* coins  = (const float*)d_in[2];
    float*       out    = (float*)d_out;

    // workspace layout (~5.1 MB total)
    char* ws = (char*)d_ws;
    int*      first_idx  = (int*)ws;                                   // 1 MB
    unsigned* bitmap     = (unsigned*)(ws + (1u << 20));               // 2 MB
    int*      wordPrefix = (int*)(ws + 3u * (1u << 20));               // 2 MB
    int*      chunkSums  = (int*)(ws + 5u * (1u << 20));               // 8 KB
    unsigned* seen       = (unsigned*)(ws + 5u*(1u<<20) + (1u<<14));   // 32 KB
    unsigned* flipbits   = (unsigned*)(ws + 5u*(1u<<20) + (1u<<14) + (1u<<15)); // 32 KB

    const int n  = N_SITES;
    const int n4 = n / 4;

    k_init<<<(NWORDS + 255) / 256, 256, 0, stream>>>(first_idx, bitmap, flipbits);
    k_seed<<<SEED_BLOCKS, SEED_TPB, 0, stream>>>((const int4*)labels, first_idx);
    k_seen<<<N_LABELS / 256, 256, 0, stream>>>(first_idx, seen);
    k_first_flat<<<n4 / 256, 256, 0, stream>>>((const int4*)labels, first_idx, seen, n4);
    k_scatter<<<N_LABELS / 256, 256, 0, stream>>>(first_idx, bitmap);
    k_chunk_sums<<<NCHUNKS, WPC, 0, stream>>>(bitmap, chunkSums);
    k_scan<<<1, 256, 0, stream>>>(chunkSums, NCHUNKS);
    k_word_prefix<<<NCHUNKS, WPC, 0, stream>>>(bitmap, chunkSums, wordPrefix);
    k_rank_flip<<<N_LABELS / 256, 256, 0, stream>>>(first_idx, bitmap, wordPrefix, coins, flipbits);
    k_out<<<n4 / 256, 256, 0, stream>>>((const int4*)labels, (const float4*)spins, flipbits,
                                        (float4*)out, n4);
}

// Round 6
// 172.806 us; speedup vs baseline: 1.6128x; 1.0276x over previous
//
#include <hip/hip_runtime.h>
#include <limits.h>

// Problem constants (fixed by the reference: LATTICE=(4096,4096), N_CLUSTERS=262144)
#define N_SITES   (4096 * 4096)      // 16,777,216
#define N_LABELS  262144
#define NWORDS    (N_SITES / 32)     // 524,288 bitmap words
#define NSEENW    (N_LABELS / 32)    // 8,192 seen/flip bitmap words (32 KB)
#define WPC       256                // words per chunk
#define NCHUNKS   (NWORDS / WPC)     // 2048

// Seed pass geometry: 512 blocks x 256 thr sweep sites [0, 1M) in 2 low-first
// windows, so the value filter sees a mostly-populated table in window 1.
#define SEED_SITES  (1 << 20)        // 1,048,576 sites seeded
#define SEED_BLOCKS 512
#define SEED_TPB    256

// Flat-pass geometry: 32 KB LDS probe table per block -> 5 blocks/CU max;
// 1280 blocks covers 256 CUs at full LDS budget (20 waves/CU).
#define FLAT_BLOCKS 1280
#define FLAT_TPB    256

// ---------------- kernel 1: init tables ----------------
__global__ void k_init(int* __restrict__ first_idx, unsigned* __restrict__ bitmap,
                       unsigned* __restrict__ flipbits) {
    int t = blockIdx.x * blockDim.x + threadIdx.x;
    if (t < NWORDS)   bitmap[t] = 0u;
    if (t < N_LABELS) first_idx[t] = INT_MAX;
    if (t < NSEENW)   flipbits[t] = 0u;
}

// ---------------- kernel 2a: seed pass over sites [0, 1M) ----------------
// Value-filtered atomicMin (filter correct under stale reads: values only
// decrease and every stored value was legitimately written; a stale-high read
// merely causes a redundant exact atomic).
__global__ void k_seed(const int4* __restrict__ lab4, int* __restrict__ first_idx) {
    const int STRIDE = SEED_BLOCKS * SEED_TPB;      // 131,072 int4 = 524,288 sites
    int base = blockIdx.x * blockDim.x + threadIdx.x;
    for (int t = base; t < SEED_SITES / 4; t += STRIDE) {   // 2 iterations
        int4 L = lab4[t];
        int b  = t * 4;
        if (b     < first_idx[L.x]) atomicMin(&first_idx[L.x], b);
        if (b + 1 < first_idx[L.y]) atomicMin(&first_idx[L.y], b + 1);
        if (b + 2 < first_idx[L.z]) atomicMin(&first_idx[L.z], b + 2);
        if (b + 3 < first_idx[L.w]) atomicMin(&first_idx[L.w], b + 3);
    }
}

// ---------------- kernel 2b: build 32 KB 'seen' bitmap from first_idx ----------------
// One thread per label; wave ballot composes 64 labels -> 2 words. No atomics.
__global__ void k_seen(const int* __restrict__ first_idx, unsigned* __restrict__ seen) {
    int l = blockIdx.x * blockDim.x + threadIdx.x;       // N_LABELS threads
    unsigned long long m = __ballot(first_idx[l] != INT_MAX);
    int lane = threadIdx.x & 63;
    if (lane == 0)       seen[l >> 5] = (unsigned)m;
    else if (lane == 32) seen[l >> 5] = (unsigned)(m >> 32);
}

// ---------------- kernel 2c: completion pass over ALL sites ----------------
// The 32 KB read-only 'seen' bitmap is staged in LDS: random wave64 scatter
// over 32 LDS banks averages 2 lanes/bank (measured free) vs ~60 L1 lines per
// wave-probe through the vector cache. A set bit implies first_idx[l] was
// written with an index < 2^20 by the completed seed pass, so skipping is
// exact. Clear bits (~2% of labels) take the exact filtered-atomic path.
__global__ void k_first_flat(const int4* __restrict__ lab4, int* __restrict__ first_idx,
                             const unsigned* __restrict__ seen, int n4) {
    __shared__ unsigned slds[NSEENW];
    {
        const uint4* s4 = (const uint4*)seen;
        uint4*       d4 = (uint4*)slds;
        for (int i = threadIdx.x; i < NSEENW / 4; i += blockDim.x) d4[i] = s4[i];
    }
    __syncthreads();
    const int stride = FLAT_BLOCKS * FLAT_TPB;
    for (int t = blockIdx.x * blockDim.x + threadIdx.x; t < n4; t += stride) {
        int4 L = lab4[t];
        int b  = t * 4;
        unsigned sx = slds[L.x >> 5], sy = slds[L.y >> 5];
        unsigned sz = slds[L.z >> 5], sw = slds[L.w >> 5];
        if (!((sx >> (L.x & 31)) & 1u)) { if (b     < first_idx[L.x]) atomicMin(&first_idx[L.x], b);     }
        if (!((sy >> (L.y & 31)) & 1u)) { if (b + 1 < first_idx[L.y]) atomicMin(&first_idx[L.y], b + 1); }
        if (!((sz >> (L.z & 31)) & 1u)) { if (b + 2 < first_idx[L.z]) atomicMin(&first_idx[L.z], b + 2); }
        if (!((sw >> (L.w & 31)) & 1u)) { if (b + 3 < first_idx[L.w]) atomicMin(&first_idx[L.w], b + 3); }
    }
}

// ---------------- kernel 3: scatter seed bits into occupancy bitmap ----------------
__global__ void k_scatter(const int* __restrict__ first_idx, unsigned* __restrict__ bitmap) {
    int l = blockIdx.x * blockDim.x + threadIdx.x;
    if (l >= N_LABELS) return;
    int fi = first_idx[l];
    if (fi != INT_MAX) atomicOr(&bitmap[fi >> 5], 1u << (fi & 31));
}

// ---------------- kernel 4: per-chunk popcount sums ----------------
__global__ void k_chunk_sums(const unsigned* __restrict__ bitmap, int* __restrict__ chunkSums) {
    __shared__ int waveSums[4];
    int w  = blockIdx.x * WPC + threadIdx.x;
    int pc = __popc(bitmap[w]);
    #pragma unroll
    for (int off = 32; off; off >>= 1) pc += __shfl_down(pc, off);
    if ((threadIdx.x & 63) == 0) waveSums[threadIdx.x >> 6] = pc;
    __syncthreads();
    if (threadIdx.x == 0)
        chunkSums[blockIdx.x] = waveSums[0] + waveSums[1] + waveSums[2] + waveSums[3];
}

// ---------------- kernel 5: single-block exclusive scan of chunk sums ----------------
__global__ void k_scan(int* __restrict__ data, int n) {  // n multiple of 256
    __shared__ int lds[256];
    int tid = threadIdx.x;
    int carry = 0;
    for (int base = 0; base < n; base += 256) {
        int v = data[base + tid];
        lds[tid] = v;
        __syncthreads();
        for (int off = 1; off < 256; off <<= 1) {
            int add = (tid >= off) ? lds[tid - off] : 0;
            __syncthreads();
            lds[tid] += add;
            __syncthreads();
        }
        int incl  = lds[tid];
        int total = lds[255];
        __syncthreads();                  // protect lds before next tile overwrite
        data[base + tid] = incl - v + carry;   // exclusive prefix
        carry += total;
    }
}

// ---------------- kernel 6: per-word global exclusive prefix ----------------
__global__ void k_word_prefix(const unsigned* __restrict__ bitmap,
                              const int* __restrict__ chunkPref,
                              int* __restrict__ wordPrefix) {
    __shared__ int lds[256];
    int tid = threadIdx.x;
    int w   = blockIdx.x * WPC + tid;
    int pc  = __popc(bitmap[w]);
    lds[tid] = pc;
    __syncthreads();
    for (int off = 1; off < 256; off <<= 1) {
        int add = (tid >= off) ? lds[tid - off] : 0;
        __syncthreads();
        lds[tid] += add;
        __syncthreads();
    }
    wordPrefix[w] = chunkPref[blockIdx.x] + lds[tid] - pc;  // exclusive
}

// ---------------- kernel 7: rank -> coin -> flip bit per label ----------------
__global__ void k_rank_flip(const int* __restrict__ first_idx,
                            const unsigned* __restrict__ bitmap,
                            const int* __restrict__ wordPrefix,
                            const float* __restrict__ coins,
                            unsigned* __restrict__ flipbits) {
    int l = blockIdx.x * blockDim.x + threadIdx.x;
    if (l >= N_LABELS) return;
    int fi = first_idx[l];
    if (fi == INT_MAX) return;           // label absent; its flip bit never read
    int w = fi >> 5;
    unsigned mask = (1u << (fi & 31)) - 1u;
    int rank = wordPrefix[w] + __popc(bitmap[w] & mask);
    if (coins[rank] >= 0.5f) atomicOr(&flipbits[l >> 5], 1u << (l & 31));
}

// ---------------- kernel 8: apply flips (LDS flip table + sign-bit XOR) ----------------
__global__ void k_out(const int4* __restrict__ lab4, const float4* __restrict__ sp4,
                      const unsigned* __restrict__ flipbits,
                      float4* __restrict__ out4, int n4) {
    __shared__ unsigned flds[NSEENW];
    {
        const uint4* s4 = (const uint4*)flipbits;
        uint4*       d4 = (uint4*)flds;
        for (int i = threadIdx.x; i < NSEENW / 4; i += blockDim.x) d4[i] = s4[i];
    }
    __syncthreads();
    const int stride = FLAT_BLOCKS * FLAT_TPB;
    for (int t = blockIdx.x * blockDim.x + threadIdx.x; t < n4; t += stride) {
        int4   L = lab4[t];
        float4 s = sp4[t];
        unsigned bx = (flds[L.x >> 5] >> (L.x & 31)) & 1u;
        unsigned by = (flds[L.y >> 5] >> (L.y & 31)) & 1u;
        unsigned bz = (flds[L.z >> 5] >> (L.z & 31)) & 1u;
        unsigned bw = (flds[L.w >> 5] >> (L.w & 31)) & 1u;
        float4 o;
        o.x = __uint_as_float(__float_as_uint(s.x) ^ (bx << 31));
        o.y = __uint_as_float(__float_as_uint(s.y) ^ (by << 31));
        o.z = __uint_as_float(__float_as_uint(s.z) ^ (bz << 31));
        o.w = __uint_as_float(__float_as_uint(s.w) ^ (bw << 31));
        out4[t] = o;
    }
}

extern "C" void kernel_launch(void* const* d_in, const int* in_sizes, int n_in,
                              void* d_out, int out_size, void* d_ws, size_t ws_size,
                              hipStream_t stream) {
    const float* spins  = (const float*)d_in[0];
    const int*   labels = (const int*)d_in[1];
    const float* coins  = (const float*)d_in[2];
    float*       out    = (float*)d_out;

    // workspace layout (~5.1 MB total)
    char* ws = (char*)d_ws;
    int*      first_idx  = (int*)ws;                                   // 1 MB
    unsigned* bitmap     = (unsigned*)(ws + (1u << 20));               // 2 MB
    int*      wordPrefix = (int*)(ws + 3u * (1u << 20));               // 2 MB
    int*      chunkSums  = (int*)(ws + 5u * (1u << 20));               // 8 KB
    unsigned* seen       = (unsigned*)(ws + 5u*(1u<<20) + (1u<<14));   // 32 KB
    unsigned* flipbits   = (unsigned*)(ws + 5u*(1u<<20) + (1u<<14) + (1u<<15)); // 32 KB

    const int n  = N_SITES;
    const int n4 = n / 4;

    k_init<<<(NWORDS + 255) / 256, 256, 0, stream>>>(first_idx, bitmap, flipbits);
    k_seed<<<SEED_BLOCKS, SEED_TPB, 0, stream>>>((const int4*)labels, first_idx);
    k_seen<<<N_LABELS / 256, 256, 0, stream>>>(first_idx, seen);
    k_first_flat<<<FLAT_BLOCKS, FLAT_TPB, 0, stream>>>((const int4*)labels, first_idx, seen, n4);
    k_scatter<<<N_LABELS / 256, 256, 0, stream>>>(first_idx, bitmap);
    k_chunk_sums<<<NCHUNKS, WPC, 0, stream>>>(bitmap, chunkSums);
    k_scan<<<1, 256, 0, stream>>>(chunkSums, NCHUNKS);
    k_word_prefix<<<NCHUNKS, WPC, 0, stream>>>(bitmap, chunkSums, wordPrefix);
    k_rank_flip<<<N_LABELS / 256, 256, 0, stream>>>(first_idx, bitmap, wordPrefix, coins, flipbits);
    k_out<<<FLAT_BLOCKS, FLAT_TPB, 0, stream>>>((const int4*)labels, (const float4*)spins, flipbits,
                                                (float4*)out, n4);
}

// Round 7
// 152.979 us; speedup vs baseline: 1.8218x; 1.1296x over previous
//
#include <hip/hip_runtime.h>
#include <limits.h>

// Problem constants (fixed by the reference: LATTICE=(4096,4096), N_CLUSTERS=262144)
#define N_SITES   (4096 * 4096)      // 16,777,216
#define N_LABELS  262144
#define NWORDS    (N_SITES / 32)     // 524,288 bitmap words
#define NSEENW    (N_LABELS / 32)    // 8,192 seen/flip bitmap words (32 KB)
#define WPC       256                // words per chunk
#define NCHUNKS   (NWORDS / WPC)     // 2048

// Seed pass geometry: 512 blocks x 256 thr sweep sites [0, 1M) in 2 low-first
// windows, so the value filter sees a mostly-populated table in window 1.
#define SEED_SITES  (1 << 20)        // 1,048,576 sites seeded
#define SEED_BLOCKS 512
#define SEED_TPB    256

// Flat-pass geometry: 32 KB LDS probe table per block. R6 showed a 32 KB
// block occupies a 64 KB LDS slot -> only 2 blocks/CU resident; with 256
// threads that was 8 waves/CU (26% occupancy, latency-bound). Carry 16
// waves per block instead: 1024 thr x 512 blocks = 2 blocks/CU = 32 waves/CU.
#define FLAT_BLOCKS 512
#define FLAT_TPB    1024

// ---------------- kernel 1: init tables ----------------
__global__ void k_init(int* __restrict__ first_idx, unsigned* __restrict__ bitmap,
                       unsigned* __restrict__ flipbits) {
    int t = blockIdx.x * blockDim.x + threadIdx.x;
    if (t < NWORDS)   bitmap[t] = 0u;
    if (t < N_LABELS) first_idx[t] = INT_MAX;
    if (t < NSEENW)   flipbits[t] = 0u;
}

// ---------------- kernel 2a: seed pass over sites [0, 1M) ----------------
// Value-filtered atomicMin (filter correct under stale reads: values only
// decrease and every stored value was legitimately written; a stale-high read
// merely causes a redundant exact atomic).
__global__ void k_seed(const int4* __restrict__ lab4, int* __restrict__ first_idx) {
    const int STRIDE = SEED_BLOCKS * SEED_TPB;      // 131,072 int4 = 524,288 sites
    int base = blockIdx.x * blockDim.x + threadIdx.x;
    for (int t = base; t < SEED_SITES / 4; t += STRIDE) {   // 2 iterations
        int4 L = lab4[t];
        int b  = t * 4;
        if (b     < first_idx[L.x]) atomicMin(&first_idx[L.x], b);
        if (b + 1 < first_idx[L.y]) atomicMin(&first_idx[L.y], b + 1);
        if (b + 2 < first_idx[L.z]) atomicMin(&first_idx[L.z], b + 2);
        if (b + 3 < first_idx[L.w]) atomicMin(&first_idx[L.w], b + 3);
    }
}

// ---------------- kernel 2b: build 32 KB 'seen' bitmap from first_idx ----------------
// One thread per label; wave ballot composes 64 labels -> 2 words. No atomics.
__global__ void k_seen(const int* __restrict__ first_idx, unsigned* __restrict__ seen) {
    int l = blockIdx.x * blockDim.x + threadIdx.x;       // N_LABELS threads
    unsigned long long m = __ballot(first_idx[l] != INT_MAX);
    int lane = threadIdx.x & 63;
    if (lane == 0)       seen[l >> 5] = (unsigned)m;
    else if (lane == 32) seen[l >> 5] = (unsigned)(m >> 32);
}

// ---------------- kernel 2c: completion pass over ALL sites ----------------
// The 32 KB read-only 'seen' bitmap is staged in LDS: random wave64 scatter
// over 32 LDS banks averages ~2 lanes/bank (free) vs ~60 L1 lines per
// wave-probe through the vector cache. A set bit implies first_idx[l] was
// written with an index < 2^20 by the completed seed pass, so skipping is
// exact. Clear bits (~2% of labels) take the exact filtered-atomic path.
__global__ void __launch_bounds__(FLAT_TPB)
k_first_flat(const int4* __restrict__ lab4, int* __restrict__ first_idx,
             const unsigned* __restrict__ seen, int n4) {
    __shared__ unsigned slds[NSEENW];
    {
        const uint4* s4 = (const uint4*)seen;
        uint4*       d4 = (uint4*)slds;
        for (int i = threadIdx.x; i < NSEENW / 4; i += blockDim.x) d4[i] = s4[i];
    }
    __syncthreads();
    const int stride = FLAT_BLOCKS * FLAT_TPB;
    for (int t = blockIdx.x * blockDim.x + threadIdx.x; t < n4; t += stride) {
        int4 L = lab4[t];
        int b  = t * 4;
        unsigned sx = slds[L.x >> 5], sy = slds[L.y >> 5];
        unsigned sz = slds[L.z >> 5], sw = slds[L.w >> 5];
        if (!((sx >> (L.x & 31)) & 1u)) { if (b     < first_idx[L.x]) atomicMin(&first_idx[L.x], b);     }
        if (!((sy >> (L.y & 31)) & 1u)) { if (b + 1 < first_idx[L.y]) atomicMin(&first_idx[L.y], b + 1); }
        if (!((sz >> (L.z & 31)) & 1u)) { if (b + 2 < first_idx[L.z]) atomicMin(&first_idx[L.z], b + 2); }
        if (!((sw >> (L.w & 31)) & 1u)) { if (b + 3 < first_idx[L.w]) atomicMin(&first_idx[L.w], b + 3); }
    }
}

// ---------------- kernel 3: scatter seed bits into occupancy bitmap ----------------
__global__ void k_scatter(const int* __restrict__ first_idx, unsigned* __restrict__ bitmap) {
    int l = blockIdx.x * blockDim.x + threadIdx.x;
    if (l >= N_LABELS) return;
    int fi = first_idx[l];
    if (fi != INT_MAX) atomicOr(&bitmap[fi >> 5], 1u << (fi & 31));
}

// ---------------- kernel 4: per-chunk popcount sums ----------------
__global__ void k_chunk_sums(const unsigned* __restrict__ bitmap, int* __restrict__ chunkSums) {
    __shared__ int waveSums[4];
    int w  = blockIdx.x * WPC + threadIdx.x;
    int pc = __popc(bitmap[w]);
    #pragma unroll
    for (int off = 32; off; off >>= 1) pc += __shfl_down(pc, off);
    if ((threadIdx.x & 63) == 0) waveSums[threadIdx.x >> 6] = pc;
    __syncthreads();
    if (threadIdx.x == 0)
        chunkSums[blockIdx.x] = waveSums[0] + waveSums[1] + waveSums[2] + waveSums[3];
}

// ---------------- kernel 5: single-block exclusive scan of chunk sums ----------------
__global__ void k_scan(int* __restrict__ data, int n) {  // n multiple of 256
    __shared__ int lds[256];
    int tid = threadIdx.x;
    int carry = 0;
    for (int base = 0; base < n; base += 256) {
        int v = data[base + tid];
        lds[tid] = v;
        __syncthreads();
        for (int off = 1; off < 256; off <<= 1) {
            int add = (tid >= off) ? lds[tid - off] : 0;
            __syncthreads();
            lds[tid] += add;
            __syncthreads();
        }
        int incl  = lds[tid];
        int total = lds[255];
        __syncthreads();                  // protect lds before next tile overwrite
        data[base + tid] = incl - v + carry;   // exclusive prefix
        carry += total;
    }
}

// ---------------- kernel 6: per-word global exclusive prefix ----------------
__global__ void k_word_prefix(const unsigned* __restrict__ bitmap,
                              const int* __restrict__ chunkPref,
                              int* __restrict__ wordPrefix) {
    __shared__ int lds[256];
    int tid = threadIdx.x;
    int w   = blockIdx.x * WPC + tid;
    int pc  = __popc(bitmap[w]);
    lds[tid] = pc;
    __syncthreads();
    for (int off = 1; off < 256; off <<= 1) {
        int add = (tid >= off) ? lds[tid - off] : 0;
        __syncthreads();
        lds[tid] += add;
        __syncthreads();
    }
    wordPrefix[w] = chunkPref[blockIdx.x] + lds[tid] - pc;  // exclusive
}

// ---------------- kernel 7: rank -> coin -> flip bit per label ----------------
__global__ void k_rank_flip(const int* __restrict__ first_idx,
                            const unsigned* __restrict__ bitmap,
                            const int* __restrict__ wordPrefix,
                            const float* __restrict__ coins,
                            unsigned* __restrict__ flipbits) {
    int l = blockIdx.x * blockDim.x + threadIdx.x;
    if (l >= N_LABELS) return;
    int fi = first_idx[l];
    if (fi == INT_MAX) return;           // label absent; its flip bit never read
    int w = fi >> 5;
    unsigned mask = (1u << (fi & 31)) - 1u;
    int rank = wordPrefix[w] + __popc(bitmap[w] & mask);
    if (coins[rank] >= 0.5f) atomicOr(&flipbits[l >> 5], 1u << (l & 31));
}

// ---------------- kernel 8: apply flips (LDS flip table + sign-bit XOR) ----------------
__global__ void __launch_bounds__(FLAT_TPB)
k_out(const int4* __restrict__ lab4, const float4* __restrict__ sp4,
      const unsigned* __restrict__ flipbits,
      float4* __restrict__ out4, int n4) {
    __shared__ unsigned flds[NSEENW];
    {
        const uint4* s4 = (const uint4*)flipbits;
        uint4*       d4 = (uint4*)flds;
        for (int i = threadIdx.x; i < NSEENW / 4; i += blockDim.x) d4[i] = s4[i];
    }
    __syncthreads();
    const int stride = FLAT_BLOCKS * FLAT_TPB;
    for (int t = blockIdx.x * blockDim.x + threadIdx.x; t < n4; t += stride) {
        int4   L = lab4[t];
        float4 s = sp4[t];
        unsigned bx = (flds[L.x >> 5] >> (L.x & 31)) & 1u;
        unsigned by = (flds[L.y >> 5] >> (L.y & 31)) & 1u;
        unsigned bz = (flds[L.z >> 5] >> (L.z & 31)) & 1u;
        unsigned bw = (flds[L.w >> 5] >> (L.w & 31)) & 1u;
        float4 o;
        o.x = __uint_as_float(__float_as_uint(s.x) ^ (bx << 31));
        o.y = __uint_as_float(__float_as_uint(s.y) ^ (by << 31));
        o.z = __uint_as_float(__float_as_uint(s.z) ^ (bz << 31));
        o.w = __uint_as_float(__float_as_uint(s.w) ^ (bw << 31));
        out4[t] = o;
    }
}

extern "C" void kernel_launch(void* const* d_in, const int* in_sizes, int n_in,
                              void* d_out, int out_size, void* d_ws, size_t ws_size,
                              hipStream_t stream) {
    const float* spins  = (const float*)d_in[0];
    const int*   labels = (const int*)d_in[1];
    const float* coins  = (const float*)d_in[2];
    float*       out    = (float*)d_out;

    // workspace layout (~5.1 MB total)
    char* ws = (char*)d_ws;
    int*      first_idx  = (int*)ws;                                   // 1 MB
    unsigned* bitmap     = (unsigned*)(ws + (1u << 20));               // 2 MB
    int*      wordPrefix = (int*)(ws + 3u * (1u << 20));               // 2 MB
    int*      chunkSums  = (int*)(ws + 5u * (1u << 20));               // 8 KB
    unsigned* seen       = (unsigned*)(ws + 5u*(1u<<20) + (1u<<14));   // 32 KB
    unsigned* flipbits   = (unsigned*)(ws + 5u*(1u<<20) + (1u<<14) + (1u<<15)); // 32 KB

    const int n  = N_SITES;
    const int n4 = n / 4;

    k_init<<<(NWORDS + 255) / 256, 256, 0, stream>>>(first_idx, bitmap, flipbits);
    k_seed<<<SEED_BLOCKS, SEED_TPB, 0, stream>>>((const int4*)labels, first_idx);
    k_seen<<<N_LABELS / 256, 256, 0, stream>>>(first_idx, seen);
    k_first_flat<<<FLAT_BLOCKS, FLAT_TPB, 0, stream>>>((const int4*)labels, first_idx, seen, n4);
    k_scatter<<<N_LABELS / 256, 256, 0, stream>>>(first_idx, bitmap);
    k_chunk_sums<<<NCHUNKS, WPC, 0, stream>>>(bitmap, chunkSums);
    k_scan<<<1, 256, 0, stream>>>(chunkSums, NCHUNKS);
    k_word_prefix<<<NCHUNKS, WPC, 0, stream>>>(bitmap, chunkSums, wordPrefix);
    k_rank_flip<<<N_LABELS / 256, 256, 0, stream>>>(first_idx, bitmap, wordPrefix, coins, flipbits);
    k_out<<<FLAT_BLOCKS, FLAT_TPB, 0, stream>>>((const int4*)labels, (const float4*)spins, flipbits,
                                                (float4*)out, n4);
}

// Round 8
// 152.026 us; speedup vs baseline: 1.8333x; 1.0063x over previous
//
#include <hip/hip_runtime.h>
#include <limits.h>

// Problem constants (fixed by the reference: LATTICE=(4096,4096), N_CLUSTERS=262144)
#define N_SITES   (4096 * 4096)      // 16,777,216
#define N_LABELS  262144
#define NWORDS    (N_SITES / 32)     // 524,288 bitmap words
#define NSEENW    (N_LABELS / 32)    // 8,192 seen/flip bitmap words (32 KB)
#define WPC       256                // words per chunk
#define NCHUNKS   (NWORDS / WPC)     // 2048

// Seed geometry: 4 windowed LAUNCHES of 256K sites each (kernel boundaries
// quiesce the table so filter reads don't race atomic write-invalidations).
#define SEED_WIN_SITES  (1 << 18)    // 262,144 sites per window
#define SEED_WIN_INT4   (SEED_WIN_SITES / 4)   // 65,536 int4
#define SEED_TPB        256

// Flat-pass geometry: 32 KB LDS probe table, 1024 thr/block, 512 blocks
// = 2 blocks/CU (64 KB LDS slots) x 16 waves = 32 waves/CU. 2-way ILP.
#define FLAT_BLOCKS 512
#define FLAT_TPB    1024

// ---------------- kernel 1: init tables ----------------
__global__ void k_init(int* __restrict__ first_idx, unsigned* __restrict__ bitmap,
                       unsigned* __restrict__ flipbits) {
    int t = blockIdx.x * blockDim.x + threadIdx.x;
    if (t < NWORDS)   bitmap[t] = 0u;
    if (t < N_LABELS) first_idx[t] = INT_MAX;
    if (t < NSEENW)   flipbits[t] = 0u;
}

// ---------------- kernel 2a: one seed window [base4, base4 + SEED_WIN_INT4) ----------------
// Value-filtered atomicMin. Filter is correct under stale reads (values only
// decrease; every stored value was legitimately written), and the per-window
// kernel boundary means reads in window k see a quiescent table populated by
// windows 0..k-1 — no concurrent write-invalidation thrash.
__global__ void k_seed_win(const int4* __restrict__ lab4, int* __restrict__ first_idx,
                           int base4) {
    int t = base4 + blockIdx.x * blockDim.x + threadIdx.x;   // one int4 per thread
    int4 L = lab4[t];
    int b  = t * 4;
    if (b     < first_idx[L.x]) atomicMin(&first_idx[L.x], b);
    if (b + 1 < first_idx[L.y]) atomicMin(&first_idx[L.y], b + 1);
    if (b + 2 < first_idx[L.z]) atomicMin(&first_idx[L.z], b + 2);
    if (b + 3 < first_idx[L.w]) atomicMin(&first_idx[L.w], b + 3);
}

// ---------------- kernel 2b: build 32 KB 'seen' bitmap from first_idx ----------------
// One thread per label; wave ballot composes 64 labels -> 2 words. No atomics.
__global__ void k_seen(const int* __restrict__ first_idx, unsigned* __restrict__ seen) {
    int l = blockIdx.x * blockDim.x + threadIdx.x;       // N_LABELS threads
    unsigned long long m = __ballot(first_idx[l] != INT_MAX);
    int lane = threadIdx.x & 63;
    if (lane == 0)       seen[l >> 5] = (unsigned)m;
    else if (lane == 32) seen[l >> 5] = (unsigned)(m >> 32);
}

// ---------------- kernel 2c: completion pass over ALL sites ----------------
// 32 KB read-only 'seen' bitmap staged in LDS (random wave64 scatter over 32
// banks ~2 lanes/bank = free). A set bit implies first_idx[l] holds the exact
// global min (seed covered a prefix of the raster order), so skipping is
// exact. Clear bits (~2% of labels) take the exact filtered-atomic path.
// 2-way ILP: two independent int4 streams in flight per thread.
__global__ void __launch_bounds__(FLAT_TPB)
k_first_flat(const int4* __restrict__ lab4, int* __restrict__ first_idx,
             const unsigned* __restrict__ seen, int n4) {
    __shared__ unsigned slds[NSEENW];
    {
        const uint4* s4 = (const uint4*)seen;
        uint4*       d4 = (uint4*)slds;
        for (int i = threadIdx.x; i < NSEENW / 4; i += blockDim.x) d4[i] = s4[i];
    }
    __syncthreads();
    const int stride = FLAT_BLOCKS * FLAT_TPB;           // n4 = 8 * stride
    for (int t = blockIdx.x * blockDim.x + threadIdx.x; t < n4; t += 2 * stride) {
        int4 La = lab4[t];
        int4 Lb = lab4[t + stride];
        int a = t * 4, b = (t + stride) * 4;
        unsigned sax = slds[La.x >> 5], say = slds[La.y >> 5];
        unsigned saz = slds[La.z >> 5], saw = slds[La.w >> 5];
        unsigned sbx = slds[Lb.x >> 5], sby = slds[Lb.y >> 5];
        unsigned sbz = slds[Lb.z >> 5], sbw = slds[Lb.w >> 5];
        if (!((sax >> (La.x & 31)) & 1u)) { if (a     < first_idx[La.x]) atomicMin(&first_idx[La.x], a);     }
        if (!((say >> (La.y & 31)) & 1u)) { if (a + 1 < first_idx[La.y]) atomicMin(&first_idx[La.y], a + 1); }
        if (!((saz >> (La.z & 31)) & 1u)) { if (a + 2 < first_idx[La.z]) atomicMin(&first_idx[La.z], a + 2); }
        if (!((saw >> (La.w & 31)) & 1u)) { if (a + 3 < first_idx[La.w]) atomicMin(&first_idx[La.w], a + 3); }
        if (!((sbx >> (Lb.x & 31)) & 1u)) { if (b     < first_idx[Lb.x]) atomicMin(&first_idx[Lb.x], b);     }
        if (!((sby >> (Lb.y & 31)) & 1u)) { if (b + 1 < first_idx[Lb.y]) atomicMin(&first_idx[Lb.y], b + 1); }
        if (!((sbz >> (Lb.z & 31)) & 1u)) { if (b + 2 < first_idx[Lb.z]) atomicMin(&first_idx[Lb.z], b + 2); }
        if (!((sbw >> (Lb.w & 31)) & 1u)) { if (b + 3 < first_idx[Lb.w]) atomicMin(&first_idx[Lb.w], b + 3); }
    }
}

// ---------------- kernel 3: scatter seed bits into occupancy bitmap ----------------
__global__ void k_scatter(const int* __restrict__ first_idx, unsigned* __restrict__ bitmap) {
    int l = blockIdx.x * blockDim.x + threadIdx.x;
    if (l >= N_LABELS) return;
    int fi = first_idx[l];
    if (fi != INT_MAX) atomicOr(&bitmap[fi >> 5], 1u << (fi & 31));
}

// ---------------- kernel 4: per-chunk popcount sums ----------------
__global__ void k_chunk_sums(const unsigned* __restrict__ bitmap, int* __restrict__ chunkSums) {
    __shared__ int waveSums[4];
    int w  = blockIdx.x * WPC + threadIdx.x;
    int pc = __popc(bitmap[w]);
    #pragma unroll
    for (int off = 32; off; off >>= 1) pc += __shfl_down(pc, off);
    if ((threadIdx.x & 63) == 0) waveSums[threadIdx.x >> 6] = pc;
    __syncthreads();
    if (threadIdx.x == 0)
        chunkSums[blockIdx.x] = waveSums[0] + waveSums[1] + waveSums[2] + waveSums[3];
}

// ---------------- kernel 5: single-block exclusive scan of chunk sums ----------------
__global__ void k_scan(int* __restrict__ data, int n) {  // n multiple of 256
    __shared__ int lds[256];
    int tid = threadIdx.x;
    int carry = 0;
    for (int base = 0; base < n; base += 256) {
        int v = data[base + tid];
        lds[tid] = v;
        __syncthreads();
        for (int off = 1; off < 256; off <<= 1) {
            int add = (tid >= off) ? lds[tid - off] : 0;
            __syncthreads();
            lds[tid] += add;
            __syncthreads();
        }
        int incl  = lds[tid];
        int total = lds[255];
        __syncthreads();                  // protect lds before next tile overwrite
        data[base + tid] = incl - v + carry;   // exclusive prefix
        carry += total;
    }
}

// ---------------- kernel 6: per-word global exclusive prefix ----------------
__global__ void k_word_prefix(const unsigned* __restrict__ bitmap,
                              const int* __restrict__ chunkPref,
                              int* __restrict__ wordPrefix) {
    __shared__ int lds[256];
    int tid = threadIdx.x;
    int w   = blockIdx.x * WPC + tid;
    int pc  = __popc(bitmap[w]);
    lds[tid] = pc;
    __syncthreads();
    for (int off = 1; off < 256; off <<= 1) {
        int add = (tid >= off) ? lds[tid - off] : 0;
        __syncthreads();
        lds[tid] += add;
        __syncthreads();
    }
    wordPrefix[w] = chunkPref[blockIdx.x] + lds[tid] - pc;  // exclusive
}

// ---------------- kernel 7: rank -> coin -> flip bit per label ----------------
__global__ void k_rank_flip(const int* __restrict__ first_idx,
                            const unsigned* __restrict__ bitmap,
                            const int* __restrict__ wordPrefix,
                            const float* __restrict__ coins,
                            unsigned* __restrict__ flipbits) {
    int l = blockIdx.x * blockDim.x + threadIdx.x;
    if (l >= N_LABELS) return;
    int fi = first_idx[l];
    if (fi == INT_MAX) return;           // label absent; its flip bit never read
    int w = fi >> 5;
    unsigned mask = (1u << (fi & 31)) - 1u;
    int rank = wordPrefix[w] + __popc(bitmap[w] & mask);
    if (coins[rank] >= 0.5f) atomicOr(&flipbits[l >> 5], 1u << (l & 31));
}

// ---------------- kernel 8: apply flips (LDS flip table + sign-bit XOR, ILP-2) ----------------
__global__ void __launch_bounds__(FLAT_TPB)
k_out(const int4* __restrict__ lab4, const float4* __restrict__ sp4,
      const unsigned* __restrict__ flipbits,
      float4* __restrict__ out4, int n4) {
    __shared__ unsigned flds[NSEENW];
    {
        const uint4* s4 = (const uint4*)flipbits;
        uint4*       d4 = (uint4*)flds;
        for (int i = threadIdx.x; i < NSEENW / 4; i += blockDim.x) d4[i] = s4[i];
    }
    __syncthreads();
    const int stride = FLAT_BLOCKS * FLAT_TPB;           // n4 = 8 * stride
    for (int t = blockIdx.x * blockDim.x + threadIdx.x; t < n4; t += 2 * stride) {
        int4   La = lab4[t];
        int4   Lb = lab4[t + stride];
        float4 sa = sp4[t];
        float4 sb = sp4[t + stride];
        unsigned ax = (flds[La.x >> 5] >> (La.x & 31)) & 1u;
        unsigned ay = (flds[La.y >> 5] >> (La.y & 31)) & 1u;
        unsigned az = (flds[La.z >> 5] >> (La.z & 31)) & 1u;
        unsigned aw = (flds[La.w >> 5] >> (La.w & 31)) & 1u;
        unsigned bx = (flds[Lb.x >> 5] >> (Lb.x & 31)) & 1u;
        unsigned by = (flds[Lb.y >> 5] >> (Lb.y & 31)) & 1u;
        unsigned bz = (flds[Lb.z >> 5] >> (Lb.z & 31)) & 1u;
        unsigned bw = (flds[Lb.w >> 5] >> (Lb.w & 31)) & 1u;
        float4 oa, ob;
        oa.x = __uint_as_float(__float_as_uint(sa.x) ^ (ax << 31));
        oa.y = __uint_as_float(__float_as_uint(sa.y) ^ (ay << 31));
        oa.z = __uint_as_float(__float_as_uint(sa.z) ^ (az << 31));
        oa.w = __uint_as_float(__float_as_uint(sa.w) ^ (aw << 31));
        ob.x = __uint_as_float(__float_as_uint(sb.x) ^ (bx << 31));
        ob.y = __uint_as_float(__float_as_uint(sb.y) ^ (by << 31));
        ob.z = __uint_as_float(__float_as_uint(sb.z) ^ (bz << 31));
        ob.w = __uint_as_float(__float_as_uint(sb.w) ^ (bw << 31));
        out4[t]          = oa;
        out4[t + stride] = ob;
    }
}

extern "C" void kernel_launch(void* const* d_in, const int* in_sizes, int n_in,
                              void* d_out, int out_size, void* d_ws, size_t ws_size,
                              hipStream_t stream) {
    const float* spins  = (const float*)d_in[0];
    const int*   labels = (const int*)d_in[1];
    const float* coins  = (const float*)d_in[2];
    float*       out    = (float*)d_out;

    // workspace layout (~5.1 MB total)
    char* ws = (char*)d_ws;
    int*      first_idx  = (int*)ws;                                   // 1 MB
    unsigned* bitmap     = (unsigned*)(ws + (1u << 20));               // 2 MB
    int*      wordPrefix = (int*)(ws + 3u * (1u << 20));               // 2 MB
    int*      chunkSums  = (int*)(ws + 5u * (1u << 20));               // 8 KB
    unsigned* seen       = (unsigned*)(ws + 5u*(1u<<20) + (1u<<14));   // 32 KB
    unsigned* flipbits   = (unsigned*)(ws + 5u*(1u<<20) + (1u<<14) + (1u<<15)); // 32 KB

    const int n  = N_SITES;
    const int n4 = n / 4;

    k_init<<<(NWORDS + 255) / 256, 256, 0, stream>>>(first_idx, bitmap, flipbits);
    // 4 quiescent seed windows over sites [0, 1M)
    for (int w = 0; w < 4; ++w)
        k_seed_win<<<SEED_WIN_INT4 / SEED_TPB, SEED_TPB, 0, stream>>>(
            (const int4*)labels, first_idx, w * SEED_WIN_INT4);
    k_seen<<<N_LABELS / 256, 256, 0, stream>>>(first_idx, seen);
    k_first_flat<<<FLAT_BLOCKS, FLAT_TPB, 0, stream>>>((const int4*)labels, first_idx, seen, n4);
    k_scatter<<<N_LABELS / 256, 256, 0, stream>>>(first_idx, bitmap);
    k_chunk_sums<<<NCHUNKS, WPC, 0, stream>>>(bitmap, chunkSums);
    k_scan<<<1, 256, 0, stream>>>(chunkSums, NCHUNKS);
    k_word_prefix<<<NCHUNKS, WPC, 0, stream>>>(bitmap, chunkSums, wordPrefix);
    k_rank_flip<<<N_LABELS / 256, 256, 0, stream>>>(first_idx, bitmap, wordPrefix, coins, flipbits);
    k_out<<<FLAT_BLOCKS, FLAT_TPB, 0, stream>>>((const int4*)labels, (const float4*)spins, flipbits,
                                                (float4*)out, n4);
}

// Round 9
// 146.966 us; speedup vs baseline: 1.8964x; 1.0344x over previous
//
#include <hip/hip_runtime.h>
#include <limits.h>

// Problem constants (fixed by the reference: LATTICE=(4096,4096), N_CLUSTERS=262144)
#define N_SITES   (4096 * 4096)      // 16,777,216
#define N_LABELS  262144
#define NWORDS    (N_SITES / 32)     // 524,288 bitmap words
#define NSEENW    (N_LABELS / 32)    // 8,192 seen/flip bitmap words (32 KB)
#define WPC       256                // words per chunk
#define NCHUNKS   (NWORDS / WPC)     // 2048

// Seed: ONE blind pass over sites [0, 1M). R0 measured atomicMin as
// write-through-BW-limited (~32 B/atomic): 1M atomics = 32 MB writes = ~5 us.
// Blind (no filter reads) -> no coherence thrash (R7's 43 MB fetch inflation).
#define SEED_INT4   (1 << 18)        // 262,144 int4 = 1,048,576 sites
#define SEED_TPB    256

// Flat passes: 32 KB LDS probe table, 1024 thr/block (16 waves), 1024 blocks
// = 4 blocks/CU of work over ~2 resident (64 KB LDS slots) for tail slack.
// Fully unrolled 4 int4/thread.
#define FLAT_BLOCKS 1024
#define FLAT_TPB    1024
#define FLAT_THREADS (FLAT_BLOCKS * FLAT_TPB)   // 1,048,576; n4 = 4 * this

// ---------------- kernel 1: init tables ----------------
__global__ void k_init(int* __restrict__ first_idx, unsigned* __restrict__ bitmap,
                       unsigned* __restrict__ flipbits) {
    int t = blockIdx.x * blockDim.x + threadIdx.x;
    if (t < NWORDS)   bitmap[t] = 0u;
    if (t < N_LABELS) first_idx[t] = INT_MAX;
    if (t < NSEENW)   flipbits[t] = 0u;
}

// ---------------- kernel 2a: blind seed over the 1M-site prefix ----------------
// atomicMin is commutative: the final table value is the exact min over the
// prefix. If a label occurs anywhere in [0, 1M), its global first occurrence
// is also in [0, 1M), so the seeded value is the exact global first index.
__global__ void k_seed_blind(const int4* __restrict__ lab4, int* __restrict__ first_idx) {
    int t = blockIdx.x * blockDim.x + threadIdx.x;   // [0, SEED_INT4)
    int4 L = lab4[t];
    int b  = t * 4;
    atomicMin(&first_idx[L.x], b);
    atomicMin(&first_idx[L.y], b + 1);
    atomicMin(&first_idx[L.z], b + 2);
    atomicMin(&first_idx[L.w], b + 3);
}

// ---------------- kernel 2b: build 32 KB 'seen' bitmap from first_idx ----------------
// One thread per label; wave ballot composes 64 labels -> 2 words. No atomics.
__global__ void k_seen(const int* __restrict__ first_idx, unsigned* __restrict__ seen) {
    int l = blockIdx.x * blockDim.x + threadIdx.x;       // N_LABELS threads
    unsigned long long m = __ballot(first_idx[l] != INT_MAX);
    int lane = threadIdx.x & 63;
    if (lane == 0)       seen[l >> 5] = (unsigned)m;
    else if (lane == 32) seen[l >> 5] = (unsigned)(m >> 32);
}

// ---------------- kernel 2c: completion pass over ALL sites ----------------
// 32 KB read-only 'seen' bitmap staged in LDS (random wave64 scatter over 32
// banks ~2 lanes/bank = free). A set bit implies first_idx[l] already holds
// the exact global first index (seed covered a raster-order prefix), so
// skipping is exact. Clear bits (~2% of labels) take the filtered-atomic path.
__global__ void __launch_bounds__(FLAT_TPB)
k_first_flat(const int4* __restrict__ lab4, int* __restrict__ first_idx,
             const unsigned* __restrict__ seen) {
    __shared__ unsigned slds[NSEENW];
    {
        const uint4* s4 = (const uint4*)seen;
        uint4*       d4 = (uint4*)slds;
        for (int i = threadIdx.x; i < NSEENW / 4; i += blockDim.x) d4[i] = s4[i];
    }
    __syncthreads();
    int t0 = blockIdx.x * blockDim.x + threadIdx.x;
    int4 L0 = lab4[t0];
    int4 L1 = lab4[t0 + FLAT_THREADS];
    int4 L2 = lab4[t0 + 2 * FLAT_THREADS];
    int4 L3 = lab4[t0 + 3 * FLAT_THREADS];
#define PROBE(lbl, idx)                                                        \
    if (!((slds[(lbl) >> 5] >> ((lbl) & 31)) & 1u)) {                          \
        if ((idx) < first_idx[(lbl)]) atomicMin(&first_idx[(lbl)], (idx));     \
    }
    int b0 = t0 * 4, b1 = (t0 + FLAT_THREADS) * 4;
    int b2 = (t0 + 2 * FLAT_THREADS) * 4, b3 = (t0 + 3 * FLAT_THREADS) * 4;
    PROBE(L0.x, b0)     PROBE(L0.y, b0 + 1) PROBE(L0.z, b0 + 2) PROBE(L0.w, b0 + 3)
    PROBE(L1.x, b1)     PROBE(L1.y, b1 + 1) PROBE(L1.z, b1 + 2) PROBE(L1.w, b1 + 3)
    PROBE(L2.x, b2)     PROBE(L2.y, b2 + 1) PROBE(L2.z, b2 + 2) PROBE(L2.w, b2 + 3)
    PROBE(L3.x, b3)     PROBE(L3.y, b3 + 1) PROBE(L3.z, b3 + 2) PROBE(L3.w, b3 + 3)
#undef PROBE
}

// ---------------- kernel 3: scatter seed bits into occupancy bitmap ----------------
__global__ void k_scatter(const int* __restrict__ first_idx, unsigned* __restrict__ bitmap) {
    int l = blockIdx.x * blockDim.x + threadIdx.x;
    if (l >= N_LABELS) return;
    int fi = first_idx[l];
    if (fi != INT_MAX) atomicOr(&bitmap[fi >> 5], 1u << (fi & 31));
}

// ---------------- kernel 4: per-chunk popcount sums ----------------
__global__ void k_chunk_sums(const unsigned* __restrict__ bitmap, int* __restrict__ chunkSums) {
    __shared__ int waveSums[4];
    int w  = blockIdx.x * WPC + threadIdx.x;
    int pc = __popc(bitmap[w]);
    #pragma unroll
    for (int off = 32; off; off >>= 1) pc += __shfl_down(pc, off);
    if ((threadIdx.x & 63) == 0) waveSums[threadIdx.x >> 6] = pc;
    __syncthreads();
    if (threadIdx.x == 0)
        chunkSums[blockIdx.x] = waveSums[0] + waveSums[1] + waveSums[2] + waveSums[3];
}

// ---------------- kernel 5: single-block exclusive scan of chunk sums ----------------
__global__ void k_scan(int* __restrict__ data, int n) {  // n multiple of 256
    __shared__ int lds[256];
    int tid = threadIdx.x;
    int carry = 0;
    for (int base = 0; base < n; base += 256) {
        int v = data[base + tid];
        lds[tid] = v;
        __syncthreads();
        for (int off = 1; off < 256; off <<= 1) {
            int add = (tid >= off) ? lds[tid - off] : 0;
            __syncthreads();
            lds[tid] += add;
            __syncthreads();
        }
        int incl  = lds[tid];
        int total = lds[255];
        __syncthreads();                  // protect lds before next tile overwrite
        data[base + tid] = incl - v + carry;   // exclusive prefix
        carry += total;
    }
}

// ---------------- kernel 6: per-word global exclusive prefix ----------------
__global__ void k_word_prefix(const unsigned* __restrict__ bitmap,
                              const int* __restrict__ chunkPref,
                              int* __restrict__ wordPrefix) {
    __shared__ int lds[256];
    int tid = threadIdx.x;
    int w   = blockIdx.x * WPC + tid;
    int pc  = __popc(bitmap[w]);
    lds[tid] = pc;
    __syncthreads();
    for (int off = 1; off < 256; off <<= 1) {
        int add = (tid >= off) ? lds[tid - off] : 0;
        __syncthreads();
        lds[tid] += add;
        __syncthreads();
    }
    wordPrefix[w] = chunkPref[blockIdx.x] + lds[tid] - pc;  // exclusive
}

// ---------------- kernel 7: rank -> coin -> flip bit per label ----------------
__global__ void k_rank_flip(const int* __restrict__ first_idx,
                            const unsigned* __restrict__ bitmap,
                            const int* __restrict__ wordPrefix,
                            const float* __restrict__ coins,
                            unsigned* __restrict__ flipbits) {
    int l = blockIdx.x * blockDim.x + threadIdx.x;
    if (l >= N_LABELS) return;
    int fi = first_idx[l];
    if (fi == INT_MAX) return;           // label absent; its flip bit never read
    int w = fi >> 5;
    unsigned mask = (1u << (fi & 31)) - 1u;
    int rank = wordPrefix[w] + __popc(bitmap[w] & mask);
    if (coins[rank] >= 0.5f) atomicOr(&flipbits[l >> 5], 1u << (l & 31));
}

// ---------------- kernel 8: apply flips (LDS flip table + sign-bit XOR, unroll-4) ----------------
__global__ void __launch_bounds__(FLAT_TPB)
k_out(const int4* __restrict__ lab4, const float4* __restrict__ sp4,
      const unsigned* __restrict__ flipbits, float4* __restrict__ out4) {
    __shared__ unsigned flds[NSEENW];
    {
        const uint4* s4 = (const uint4*)flipbits;
        uint4*       d4 = (uint4*)flds;
        for (int i = threadIdx.x; i < NSEENW / 4; i += blockDim.x) d4[i] = s4[i];
    }
    __syncthreads();
    int t0 = blockIdx.x * blockDim.x + threadIdx.x;
    int4   L0 = lab4[t0];
    int4   L1 = lab4[t0 + FLAT_THREADS];
    int4   L2 = lab4[t0 + 2 * FLAT_THREADS];
    int4   L3 = lab4[t0 + 3 * FLAT_THREADS];
    float4 s0 = sp4[t0];
    float4 s1 = sp4[t0 + FLAT_THREADS];
    float4 s2 = sp4[t0 + 2 * FLAT_THREADS];
    float4 s3 = sp4[t0 + 3 * FLAT_THREADS];
#define FLIP1(lbl, sv) __uint_as_float(__float_as_uint(sv) ^                   \
        ((((flds[(lbl) >> 5] >> ((lbl) & 31)) & 1u)) << 31))
    float4 o0, o1, o2, o3;
    o0.x = FLIP1(L0.x, s0.x); o0.y = FLIP1(L0.y, s0.y);
    o0.z = FLIP1(L0.z, s0.z); o0.w = FLIP1(L0.w, s0.w);
    o1.x = FLIP1(L1.x, s1.x); o1.y = FLIP1(L1.y, s1.y);
    o1.z = FLIP1(L1.z, s1.z); o1.w = FLIP1(L1.w, s1.w);
    o2.x = FLIP1(L2.x, s2.x); o2.y = FLIP1(L2.y, s2.y);
    o2.z = FLIP1(L2.z, s2.z); o2.w = FLIP1(L2.w, s2.w);
    o3.x = FLIP1(L3.x, s3.x); o3.y = FLIP1(L3.y, s3.y);
    o3.z = FLIP1(L3.z, s3.z); o3.w = FLIP1(L3.w, s3.w);
#undef FLIP1
    out4[t0]                    = o0;
    out4[t0 + FLAT_THREADS]     = o1;
    out4[t0 + 2 * FLAT_THREADS] = o2;
    out4[t0 + 3 * FLAT_THREADS] = o3;
}

extern "C" void kernel_launch(void* const* d_in, const int* in_sizes, int n_in,
                              void* d_out, int out_size, void* d_ws, size_t ws_size,
                              hipStream_t stream) {
    const float* spins  = (const float*)d_in[0];
    const int*   labels = (const int*)d_in[1];
    const float* coins  = (const float*)d_in[2];
    float*       out    = (float*)d_out;

    // workspace layout (~5.1 MB total)
    char* ws = (char*)d_ws;
    int*      first_idx  = (int*)ws;                                   // 1 MB
    unsigned* bitmap     = (unsigned*)(ws + (1u << 20));               // 2 MB
    int*      wordPrefix = (int*)(ws + 3u * (1u << 20));               // 2 MB
    int*      chunkSums  = (int*)(ws + 5u * (1u << 20));               // 8 KB
    unsigned* seen       = (unsigned*)(ws + 5u*(1u<<20) + (1u<<14));   // 32 KB
    unsigned* flipbits   = (unsigned*)(ws + 5u*(1u<<20) + (1u<<14) + (1u<<15)); // 32 KB

    k_init<<<(NWORDS + 255) / 256, 256, 0, stream>>>(first_idx, bitmap, flipbits);
    k_seed_blind<<<SEED_INT4 / SEED_TPB, SEED_TPB, 0, stream>>>((const int4*)labels, first_idx);
    k_seen<<<N_LABELS / 256, 256, 0, stream>>>(first_idx, seen);
    k_first_flat<<<FLAT_BLOCKS, FLAT_TPB, 0, stream>>>((const int4*)labels, first_idx, seen);
    k_scatter<<<N_LABELS / 256, 256, 0, stream>>>(first_idx, bitmap);
    k_chunk_sums<<<NCHUNKS, WPC, 0, stream>>>(bitmap, chunkSums);
    k_scan<<<1, 256, 0, stream>>>(chunkSums, NCHUNKS);
    k_word_prefix<<<NCHUNKS, WPC, 0, stream>>>(bitmap, chunkSums, wordPrefix);
    k_rank_flip<<<N_LABELS / 256, 256, 0, stream>>>(first_idx, bitmap, wordPrefix, coins, flipbits);
    k_out<<<FLAT_BLOCKS, FLAT_TPB, 0, stream>>>((const int4*)labels, (const float4*)spins,
                                                flipbits, (float4*)out);
}

// Round 10
// 135.648 us; speedup vs baseline: 2.0546x; 1.0834x over previous
//
#include <hip/hip_runtime.h>
#include <limits.h>

// Problem constants (fixed by the reference: LATTICE=(4096,4096), N_CLUSTERS=262144)
#define N_SITES   (4096 * 4096)      // 16,777,216
#define N_LABELS  262144
#define NWORDS    (N_SITES / 32)     // 524,288 bitmap words
#define NSEENW    (N_LABELS / 32)    // 8,192 seen/flip bitmap words (32 KB)
#define WPC       256                // words per chunk
#define NCHUNKS   (NWORDS / WPC)     // 2048

// Seed: ONE blind atomicMin pass over a raster-prefix of sites. Measured
// ceiling: scattered dword atomics run at ~25 G/s (32 B write-through each),
// independent of parallelism (R0: 26.7 G/s, R9: 24.4 G/s). So seed cost =
// count * 40ns; S=768K trades -10us seed for ~+4us of flat-pass fallback
// (unseen labels: 256K*e^-3 = 12.7K -> ~816K fallback sites).
#define SEED_SITES  786432
#define SEED_INT4   (SEED_SITES / 4)             // 196,608 int4
#define SEED_TPB    256
#define SEED_BLOCKS (SEED_INT4 / SEED_TPB)       // 768
#define ZERO_BLOCKS 512                          // extra blocks zero bitmap+flipbits

// Flat passes: 32 KB LDS probe table, 1024 thr/block (16 waves), 1024 blocks.
#define FLAT_BLOCKS 1024
#define FLAT_TPB    1024
#define FLAT_THREADS (FLAT_BLOCKS * FLAT_TPB)   // 1,048,576; n4 = 4 * this

// ---------------- kernel 1: init first_idx only ----------------
__global__ void k_init(int* __restrict__ first_idx) {
    int t = blockIdx.x * blockDim.x + threadIdx.x;
    first_idx[t] = INT_MAX;                      // N_LABELS threads
}

// ---------------- kernel 2a: blind seed over the 768K-site prefix ----------------
// atomicMin is commutative: final value = exact min over the prefix. If a
// label occurs in [0, SEED_SITES), its global first occurrence does too, so
// the seeded value is the exact global first index. Extra blocks zero the
// occupancy bitmap and flip bitmap (consumed 3+ kernels later).
__global__ void k_seed_blind(const int4* __restrict__ lab4, int* __restrict__ first_idx,
                             uint4* __restrict__ bitmap4, uint4* __restrict__ flip4) {
    if (blockIdx.x < SEED_BLOCKS) {
        int t = blockIdx.x * blockDim.x + threadIdx.x;   // [0, SEED_INT4)
        int4 L = lab4[t];
        int b  = t * 4;
        atomicMin(&first_idx[L.x], b);
        atomicMin(&first_idx[L.y], b + 1);
        atomicMin(&first_idx[L.z], b + 2);
        atomicMin(&first_idx[L.w], b + 3);
    } else {
        int i = (blockIdx.x - SEED_BLOCKS) * blockDim.x + threadIdx.x;
        // bitmap: NWORDS/4 = 131072 uint4 over 512*256 = 131072 threads
        bitmap4[i] = make_uint4(0u, 0u, 0u, 0u);
        if (i < NSEENW / 4) flip4[i] = make_uint4(0u, 0u, 0u, 0u);
    }
}

// ---------------- kernel 2b: build 32 KB 'seen' bitmap from first_idx ----------------
__global__ void k_seen(const int* __restrict__ first_idx, unsigned* __restrict__ seen) {
    int l = blockIdx.x * blockDim.x + threadIdx.x;       // N_LABELS threads
    unsigned long long m = __ballot(first_idx[l] != INT_MAX);
    int lane = threadIdx.x & 63;
    if (lane == 0)       seen[l >> 5] = (unsigned)m;
    else if (lane == 32) seen[l >> 5] = (unsigned)(m >> 32);
}

// ---------------- kernel 2c: completion pass over ALL sites ----------------
// 32 KB read-only 'seen' bitmap staged in LDS (random wave64 scatter over 32
// banks ~2 lanes/bank = free). A set bit implies first_idx[l] already holds
// the exact global first index (seed covered a raster prefix), so skipping is
// exact. Clear bits (~5% of labels) take the filtered-atomic path.
__global__ void __launch_bounds__(FLAT_TPB)
k_first_flat(const int4* __restrict__ lab4, int* __restrict__ first_idx,
             const unsigned* __restrict__ seen) {
    __shared__ unsigned slds[NSEENW];
    {
        const uint4* s4 = (const uint4*)seen;
        uint4*       d4 = (uint4*)slds;
        for (int i = threadIdx.x; i < NSEENW / 4; i += blockDim.x) d4[i] = s4[i];
    }
    __syncthreads();
    int t0 = blockIdx.x * blockDim.x + threadIdx.x;
    int4 L0 = lab4[t0];
    int4 L1 = lab4[t0 + FLAT_THREADS];
    int4 L2 = lab4[t0 + 2 * FLAT_THREADS];
    int4 L3 = lab4[t0 + 3 * FLAT_THREADS];
#define PROBE(lbl, idx)                                                        \
    if (!((slds[(lbl) >> 5] >> ((lbl) & 31)) & 1u)) {                          \
        if ((idx) < first_idx[(lbl)]) atomicMin(&first_idx[(lbl)], (idx));     \
    }
    int b0 = t0 * 4, b1 = (t0 + FLAT_THREADS) * 4;
    int b2 = (t0 + 2 * FLAT_THREADS) * 4, b3 = (t0 + 3 * FLAT_THREADS) * 4;
    PROBE(L0.x, b0)     PROBE(L0.y, b0 + 1) PROBE(L0.z, b0 + 2) PROBE(L0.w, b0 + 3)
    PROBE(L1.x, b1)     PROBE(L1.y, b1 + 1) PROBE(L1.z, b1 + 2) PROBE(L1.w, b1 + 3)
    PROBE(L2.x, b2)     PROBE(L2.y, b2 + 1) PROBE(L2.z, b2 + 2) PROBE(L2.w, b2 + 3)
    PROBE(L3.x, b3)     PROBE(L3.y, b3 + 1) PROBE(L3.z, b3 + 2) PROBE(L3.w, b3 + 3)
#undef PROBE
}

// ---------------- kernel 3: scatter seed bits into occupancy bitmap ----------------
__global__ void k_scatter(const int* __restrict__ first_idx, unsigned* __restrict__ bitmap) {
    int l = blockIdx.x * blockDim.x + threadIdx.x;
    if (l >= N_LABELS) return;
    int fi = first_idx[l];
    if (fi != INT_MAX) atomicOr(&bitmap[fi >> 5], 1u << (fi & 31));
}

// ---------------- kernel 4: per-chunk popcount sums ----------------
__global__ void k_chunk_sums(const unsigned* __restrict__ bitmap, int* __restrict__ chunkSums) {
    __shared__ int waveSums[4];
    int w  = blockIdx.x * WPC + threadIdx.x;
    int pc = __popc(bitmap[w]);
    #pragma unroll
    for (int off = 32; off; off >>= 1) pc += __shfl_down(pc, off);
    if ((threadIdx.x & 63) == 0) waveSums[threadIdx.x >> 6] = pc;
    __syncthreads();
    if (threadIdx.x == 0)
        chunkSums[blockIdx.x] = waveSums[0] + waveSums[1] + waveSums[2] + waveSums[3];
}

// ---------------- kernel 5: exclusive scan of 2048 chunk sums (1 block, shfl) ----------------
__global__ void k_scan(int* __restrict__ data, int n) {   // n = 2048, 1024 threads
    __shared__ int wsum[16];
    int tid = threadIdx.x, lane = tid & 63, wid = tid >> 6;
    int carry = 0;
    for (int base = 0; base < n; base += 1024) {
        int orig = data[base + tid];
        int v = orig;
        #pragma unroll
        for (int off = 1; off < 64; off <<= 1) {
            int u = __shfl_up(v, off);
            if (lane >= off) v += u;
        }
        if (lane == 63) wsum[wid] = v;
        __syncthreads();
        if (tid < 16) {
            int w = wsum[tid];
            #pragma unroll
            for (int off = 1; off < 16; off <<= 1) {
                int u = __shfl_up(w, off);
                if (tid >= off) w += u;
            }
            wsum[tid] = w;
        }
        __syncthreads();
        int incl  = v + (wid ? wsum[wid - 1] : 0);
        int total = wsum[15];
        __syncthreads();                   // protect wsum before next tile
        data[base + tid] = incl - orig + carry;   // exclusive prefix
        carry += total;
    }
}

// ---------------- kernel 6: per-word global exclusive prefix (shfl) ----------------
__global__ void k_word_prefix(const unsigned* __restrict__ bitmap,
                              const int* __restrict__ chunkPref,
                              int* __restrict__ wordPrefix) {
    __shared__ int wsum[4];
    int tid = threadIdx.x, lane = tid & 63, wid = tid >> 6;
    int w   = blockIdx.x * WPC + tid;
    int pc  = __popc(bitmap[w]);
    int v = pc;
    #pragma unroll
    for (int off = 1; off < 64; off <<= 1) {
        int u = __shfl_up(v, off);
        if (lane >= off) v += u;
    }
    if (lane == 63) wsum[wid] = v;
    __syncthreads();
    int waveoff = 0;
    #pragma unroll
    for (int i = 0; i < 4; ++i) waveoff += (i < wid) ? wsum[i] : 0;
    wordPrefix[w] = chunkPref[blockIdx.x] + waveoff + v - pc;  // exclusive
}

// ---------------- kernel 7: rank -> coin -> flip bit per label ----------------
__global__ void k_rank_flip(const int* __restrict__ first_idx,
                            const unsigned* __restrict__ bitmap,
                            const int* __restrict__ wordPrefix,
                            const float* __restrict__ coins,
                            unsigned* __restrict__ flipbits) {
    int l = blockIdx.x * blockDim.x + threadIdx.x;
    if (l >= N_LABELS) return;
    int fi = first_idx[l];
    if (fi == INT_MAX) return;           // label absent; its flip bit never read
    int w = fi >> 5;
    unsigned mask = (1u << (fi & 31)) - 1u;
    int rank = wordPrefix[w] + __popc(bitmap[w] & mask);
    if (coins[rank] >= 0.5f) atomicOr(&flipbits[l >> 5], 1u << (l & 31));
}

// ---------------- kernel 8: apply flips (LDS flip table + sign-bit XOR, unroll-4) ----------------
__global__ void __launch_bounds__(FLAT_TPB)
k_out(const int4* __restrict__ lab4, const float4* __restrict__ sp4,
      const unsigned* __restrict__ flipbits, float4* __restrict__ out4) {
    __shared__ unsigned flds[NSEENW];
    {
        const uint4* s4 = (const uint4*)flipbits;
        uint4*       d4 = (uint4*)flds;
        for (int i = threadIdx.x; i < NSEENW / 4; i += blockDim.x) d4[i] = s4[i];
    }
    __syncthreads();
    int t0 = blockIdx.x * blockDim.x + threadIdx.x;
    int4   L0 = lab4[t0];
    int4   L1 = lab4[t0 + FLAT_THREADS];
    int4   L2 = lab4[t0 + 2 * FLAT_THREADS];
    int4   L3 = lab4[t0 + 3 * FLAT_THREADS];
    float4 s0 = sp4[t0];
    float4 s1 = sp4[t0 + FLAT_THREADS];
    float4 s2 = sp4[t0 + 2 * FLAT_THREADS];
    float4 s3 = sp4[t0 + 3 * FLAT_THREADS];
#define FLIP1(lbl, sv) __uint_as_float(__float_as_uint(sv) ^                   \
        ((((flds[(lbl) >> 5] >> ((lbl) & 31)) & 1u)) << 31))
    float4 o0, o1, o2, o3;
    o0.x = FLIP1(L0.x, s0.x); o0.y = FLIP1(L0.y, s0.y);
    o0.z = FLIP1(L0.z, s0.z); o0.w = FLIP1(L0.w, s0.w);
    o1.x = FLIP1(L1.x, s1.x); o1.y = FLIP1(L1.y, s1.y);
    o1.z = FLIP1(L1.z, s1.z); o1.w = FLIP1(L1.w, s1.w);
    o2.x = FLIP1(L2.x, s2.x); o2.y = FLIP1(L2.y, s2.y);
    o2.z = FLIP1(L2.z, s2.z); o2.w = FLIP1(L2.w, s2.w);
    o3.x = FLIP1(L3.x, s3.x); o3.y = FLIP1(L3.y, s3.y);
    o3.z = FLIP1(L3.z, s3.z); o3.w = FLIP1(L3.w, s3.w);
#undef FLIP1
    out4[t0]                    = o0;
    out4[t0 + FLAT_THREADS]     = o1;
    out4[t0 + 2 * FLAT_THREADS] = o2;
    out4[t0 + 3 * FLAT_THREADS] = o3;
}

extern "C" void kernel_launch(void* const* d_in, const int* in_sizes, int n_in,
                              void* d_out, int out_size, void* d_ws, size_t ws_size,
                              hipStream_t stream) {
    const float* spins  = (const float*)d_in[0];
    const int*   labels = (const int*)d_in[1];
    const float* coins  = (const float*)d_in[2];
    float*       out    = (float*)d_out;

    // workspace layout (~5.1 MB total)
    char* ws = (char*)d_ws;
    int*      first_idx  = (int*)ws;                                   // 1 MB
    unsigned* bitmap     = (unsigned*)(ws + (1u << 20));               // 2 MB
    int*      wordPrefix = (int*)(ws + 3u * (1u << 20));               // 2 MB
    int*      chunkSums  = (int*)(ws + 5u * (1u << 20));               // 8 KB
    unsigned* seen       = (unsigned*)(ws + 5u*(1u<<20) + (1u<<14));   // 32 KB
    unsigned* flipbits   = (unsigned*)(ws + 5u*(1u<<20) + (1u<<14) + (1u<<15)); // 32 KB

    k_init<<<N_LABELS / 256, 256, 0, stream>>>(first_idx);
    k_seed_blind<<<SEED_BLOCKS + ZERO_BLOCKS, SEED_TPB, 0, stream>>>(
        (const int4*)labels, first_idx, (uint4*)bitmap, (uint4*)flipbits);
    k_seen<<<N_LABELS / 256, 256, 0, stream>>>(first_idx, seen);
    k_first_flat<<<FLAT_BLOCKS, FLAT_TPB, 0, stream>>>((const int4*)labels, first_idx, seen);
    k_scatter<<<N_LABELS / 256, 256, 0, stream>>>(first_idx, bitmap);
    k_chunk_sums<<<NCHUNKS, WPC, 0, stream>>>(bitmap, chunkSums);
    k_scan<<<1, 1024, 0, stream>>>(chunkSums, NCHUNKS);
    k_word_prefix<<<NCHUNKS, WPC, 0, stream>>>(bitmap, chunkSums, wordPrefix);
    k_rank_flip<<<N_LABELS / 256, 256, 0, stream>>>(first_idx, bitmap, wordPrefix, coins, flipbits);
    k_out<<<FLAT_BLOCKS, FLAT_TPB, 0, stream>>>((const int4*)labels, (const float4*)spins,
                                                flipbits, (float4*)out);
}

// Round 12
// 128.222 us; speedup vs baseline: 2.1736x; 1.0579x over previous
//
#include <hip/hip_runtime.h>
#include <limits.h>

// Problem constants (fixed by the reference: LATTICE=(4096,4096), N_CLUSTERS=262144)
#define N_SITES   (4096 * 4096)      // 16,777,216
#define N_LABELS  262144
#define NWORDS    (N_SITES / 32)     // 524,288 bitmap words
#define NSEENW    (N_LABELS / 32)    // 8,192 seen/flip bitmap words (32 KB)
#define WPC       256                // words per chunk
#define NCHUNKS   (NWORDS / WPC)     // 2048

// Seed: ONE blind atomicMin pass over a raster-prefix of sites. Measured
// ceiling: scattered dword atomics run at ~25 G/s (32 B write-through each),
// independent of parallelism. Seed cost ~= count * 40ns.
#define SEED_SITES  786432
#define SEED_INT4   (SEED_SITES / 4)             // 196,608 int4
#define SEED_TPB    256
#define SEED_BLOCKS (SEED_INT4 / SEED_TPB)       // 768
#define ZERO_BLOCKS 512                          // extra blocks zero the 2 MB bitmap

// Flat passes: persistent geometry. 512 blocks x 1024 thr = exactly 2
// resident blocks/CU (32 KB LDS -> 64 KB slot), 32 waves/CU. Each block
// stages its LDS table ONCE, then loops 2 iterations of unroll-4
// (8 int4/thread total). No second scheduling round, no re-staging.
#define FLAT_BLOCKS 512
#define FLAT_TPB    1024
#define FLAT_THREADS (FLAT_BLOCKS * FLAT_TPB)   // 524,288; n4 = 8 * this

// plain ext-vector type for nontemporal builtins (HIP_vector_type is rejected)
typedef float f32x4 __attribute__((ext_vector_type(4)));

// ---------------- kernel 1: init first_idx only ----------------
__global__ void k_init(int* __restrict__ first_idx) {
    int t = blockIdx.x * blockDim.x + threadIdx.x;
    first_idx[t] = INT_MAX;                      // N_LABELS threads
}

// ---------------- kernel 2a: blind seed over the 768K-site prefix ----------------
// atomicMin is commutative: final value = exact min over the prefix. If a
// label occurs in [0, SEED_SITES), its global first occurrence does too, so
// the seeded value is the exact global first index. Extra blocks zero the
// occupancy bitmap (consumed by k_scatter's atomicOr 3 kernels later).
__global__ void k_seed_blind(const int4* __restrict__ lab4, int* __restrict__ first_idx,
                             uint4* __restrict__ bitmap4) {
    if (blockIdx.x < SEED_BLOCKS) {
        int t = blockIdx.x * blockDim.x + threadIdx.x;   // [0, SEED_INT4)
        int4 L = lab4[t];
        int b  = t * 4;
        atomicMin(&first_idx[L.x], b);
        atomicMin(&first_idx[L.y], b + 1);
        atomicMin(&first_idx[L.z], b + 2);
        atomicMin(&first_idx[L.w], b + 3);
    } else {
        int i = (blockIdx.x - SEED_BLOCKS) * blockDim.x + threadIdx.x;
        bitmap4[i] = make_uint4(0u, 0u, 0u, 0u);   // 131,072 uint4 over 131,072 thr
    }
}

// ---------------- kernel 2b: build 32 KB 'seen' bitmap from first_idx ----------------
__global__ void k_seen(const int* __restrict__ first_idx, unsigned* __restrict__ seen) {
    int l = blockIdx.x * blockDim.x + threadIdx.x;       // N_LABELS threads
    unsigned long long m = __ballot(first_idx[l] != INT_MAX);
    int lane = threadIdx.x & 63;
    if (lane == 0)       seen[l >> 5] = (unsigned)m;
    else if (lane == 32) seen[l >> 5] = (unsigned)(m >> 32);
}

// ---------------- kernel 2c: completion pass over ALL sites (persistent) ----------------
// 32 KB read-only 'seen' bitmap staged in LDS once per block. A set bit
// implies first_idx[l] already holds the exact global first index (seed
// covered a raster prefix), so skipping is exact. Clear bits (~5% of labels)
// take the filtered-atomic path.
__global__ void __launch_bounds__(FLAT_TPB)
k_first_flat(const int4* __restrict__ lab4, int* __restrict__ first_idx,
             const unsigned* __restrict__ seen) {
    __shared__ unsigned slds[NSEENW];
    {
        const uint4* s4 = (const uint4*)seen;
        uint4*       d4 = (uint4*)slds;
        for (int i = threadIdx.x; i < NSEENW / 4; i += blockDim.x) d4[i] = s4[i];
    }
    __syncthreads();
    int base = blockIdx.x * blockDim.x + threadIdx.x;
#define PROBE(lbl, idx)                                                        \
    if (!((slds[(lbl) >> 5] >> ((lbl) & 31)) & 1u)) {                          \
        if ((idx) < first_idx[(lbl)]) atomicMin(&first_idx[(lbl)], (idx));     \
    }
    #pragma unroll
    for (int it = 0; it < 2; ++it) {
        int t0 = base + it * 4 * FLAT_THREADS;
        int4 L0 = lab4[t0];
        int4 L1 = lab4[t0 + FLAT_THREADS];
        int4 L2 = lab4[t0 + 2 * FLAT_THREADS];
        int4 L3 = lab4[t0 + 3 * FLAT_THREADS];
        int b0 = t0 * 4, b1 = (t0 + FLAT_THREADS) * 4;
        int b2 = (t0 + 2 * FLAT_THREADS) * 4, b3 = (t0 + 3 * FLAT_THREADS) * 4;
        PROBE(L0.x, b0)     PROBE(L0.y, b0 + 1) PROBE(L0.z, b0 + 2) PROBE(L0.w, b0 + 3)
        PROBE(L1.x, b1)     PROBE(L1.y, b1 + 1) PROBE(L1.z, b1 + 2) PROBE(L1.w, b1 + 3)
        PROBE(L2.x, b2)     PROBE(L2.y, b2 + 1) PROBE(L2.z, b2 + 2) PROBE(L2.w, b2 + 3)
        PROBE(L3.x, b3)     PROBE(L3.y, b3 + 1) PROBE(L3.z, b3 + 2) PROBE(L3.w, b3 + 3)
    }
#undef PROBE
}

// ---------------- kernel 3: scatter seed bits into occupancy bitmap ----------------
__global__ void k_scatter(const int* __restrict__ first_idx, unsigned* __restrict__ bitmap) {
    int l = blockIdx.x * blockDim.x + threadIdx.x;
    if (l >= N_LABELS) return;
    int fi = first_idx[l];
    if (fi != INT_MAX) atomicOr(&bitmap[fi >> 5], 1u << (fi & 31));
}

// ---------------- kernel 4: per-chunk popcount sums ----------------
__global__ void k_chunk_sums(const unsigned* __restrict__ bitmap, int* __restrict__ chunkSums) {
    __shared__ int waveSums[4];
    int w  = blockIdx.x * WPC + threadIdx.x;
    int pc = __popc(bitmap[w]);
    #pragma unroll
    for (int off = 32; off; off >>= 1) pc += __shfl_down(pc, off);
    if ((threadIdx.x & 63) == 0) waveSums[threadIdx.x >> 6] = pc;
    __syncthreads();
    if (threadIdx.x == 0)
        chunkSums[blockIdx.x] = waveSums[0] + waveSums[1] + waveSums[2] + waveSums[3];
}

// ---------------- kernel 5: exclusive scan of 2048 chunk sums (1 block, shfl) ----------------
__global__ void k_scan(int* __restrict__ data, int n) {   // n = 2048, 1024 threads
    __shared__ int wsum[16];
    int tid = threadIdx.x, lane = tid & 63, wid = tid >> 6;
    int carry = 0;
    for (int base = 0; base < n; base += 1024) {
        int orig = data[base + tid];
        int v = orig;
        #pragma unroll
        for (int off = 1; off < 64; off <<= 1) {
            int u = __shfl_up(v, off);
            if (lane >= off) v += u;
        }
        if (lane == 63) wsum[wid] = v;
        __syncthreads();
        if (tid < 16) {
            int w = wsum[tid];
            #pragma unroll
            for (int off = 1; off < 16; off <<= 1) {
                int u = __shfl_up(w, off);
                if (tid >= off) w += u;
            }
            wsum[tid] = w;
        }
        __syncthreads();
        int incl  = v + (wid ? wsum[wid - 1] : 0);
        int total = wsum[15];
        __syncthreads();                   // protect wsum before next tile
        data[base + tid] = incl - orig + carry;   // exclusive prefix
        carry += total;
    }
}

// ---------------- kernel 6: per-word global exclusive prefix (shfl) ----------------
__global__ void k_word_prefix(const unsigned* __restrict__ bitmap,
                              const int* __restrict__ chunkPref,
                              int* __restrict__ wordPrefix) {
    __shared__ int wsum[4];
    int tid = threadIdx.x, lane = tid & 63, wid = tid >> 6;
    int w   = blockIdx.x * WPC + tid;
    int pc  = __popc(bitmap[w]);
    int v = pc;
    #pragma unroll
    for (int off = 1; off < 64; off <<= 1) {
        int u = __shfl_up(v, off);
        if (lane >= off) v += u;
    }
    if (lane == 63) wsum[wid] = v;
    __syncthreads();
    int waveoff = 0;
    #pragma unroll
    for (int i = 0; i < 4; ++i) waveoff += (i < wid) ? wsum[i] : 0;
    wordPrefix[w] = chunkPref[blockIdx.x] + waveoff + v - pc;  // exclusive
}

// ---------------- kernel 7: rank -> coin -> flip bit (ballot, NO atomics) ----------------
// Threads are label-indexed (consecutive), so 64 flip decisions compose into
// one wave ballot -> 2 plain word stores. Absent labels store 0 (never read).
// Writes EVERY flipbits word, so no prior zeroing of flipbits is needed.
__global__ void k_rank_flip(const int* __restrict__ first_idx,
                            const unsigned* __restrict__ bitmap,
                            const int* __restrict__ wordPrefix,
                            const float* __restrict__ coins,
                            unsigned* __restrict__ flipbits) {
    int l = blockIdx.x * blockDim.x + threadIdx.x;   // N_LABELS threads
    int fi = first_idx[l];
    bool flip = false;
    if (fi != INT_MAX) {
        int w = fi >> 5;
        unsigned mask = (1u << (fi & 31)) - 1u;
        int rank = wordPrefix[w] + __popc(bitmap[w] & mask);
        flip = (coins[rank] >= 0.5f);
    }
    unsigned long long m = __ballot(flip);
    int lane = threadIdx.x & 63;
    if (lane == 0)       flipbits[l >> 5] = (unsigned)m;
    else if (lane == 32) flipbits[l >> 5] = (unsigned)(m >> 32);
}

// ---------------- kernel 8: apply flips (persistent, LDS table, nt streams) ----------------
__global__ void __launch_bounds__(FLAT_TPB)
k_out(const int4* __restrict__ lab4, const float* __restrict__ spins,
      const unsigned* __restrict__ flipbits, float* __restrict__ out) {
    __shared__ unsigned flds[NSEENW];
    {
        const uint4* s4 = (const uint4*)flipbits;
        uint4*       d4 = (uint4*)flds;
        for (int i = threadIdx.x; i < NSEENW / 4; i += blockDim.x) d4[i] = s4[i];
    }
    __syncthreads();
    const f32x4* sp4  = (const f32x4*)spins;
    f32x4*       out4 = (f32x4*)out;
    int base = blockIdx.x * blockDim.x + threadIdx.x;
#define FLIP1(lbl, sv) __uint_as_float(__float_as_uint(sv) ^                   \
        ((((flds[(lbl) >> 5] >> ((lbl) & 31)) & 1u)) << 31))
    #pragma unroll
    for (int it = 0; it < 2; ++it) {
        int t0 = base + it * 4 * FLAT_THREADS;
        int4  L0 = lab4[t0];
        int4  L1 = lab4[t0 + FLAT_THREADS];
        int4  L2 = lab4[t0 + 2 * FLAT_THREADS];
        int4  L3 = lab4[t0 + 3 * FLAT_THREADS];
        f32x4 s0 = __builtin_nontemporal_load(&sp4[t0]);
        f32x4 s1 = __builtin_nontemporal_load(&sp4[t0 + FLAT_THREADS]);
        f32x4 s2 = __builtin_nontemporal_load(&sp4[t0 + 2 * FLAT_THREADS]);
        f32x4 s3 = __builtin_nontemporal_load(&sp4[t0 + 3 * FLAT_THREADS]);
        f32x4 o0, o1, o2, o3;
        o0.x = FLIP1(L0.x, s0.x); o0.y = FLIP1(L0.y, s0.y);
        o0.z = FLIP1(L0.z, s0.z); o0.w = FLIP1(L0.w, s0.w);
        o1.x = FLIP1(L1.x, s1.x); o1.y = FLIP1(L1.y, s1.y);
        o1.z = FLIP1(L1.z, s1.z); o1.w = FLIP1(L1.w, s1.w);
        o2.x = FLIP1(L2.x, s2.x); o2.y = FLIP1(L2.y, s2.y);
        o2.z = FLIP1(L2.z, s2.z); o2.w = FLIP1(L2.w, s2.w);
        o3.x = FLIP1(L3.x, s3.x); o3.y = FLIP1(L3.y, s3.y);
        o3.z = FLIP1(L3.z, s3.z); o3.w = FLIP1(L3.w, s3.w);
        __builtin_nontemporal_store(o0, &out4[t0]);
        __builtin_nontemporal_store(o1, &out4[t0 + FLAT_THREADS]);
        __builtin_nontemporal_store(o2, &out4[t0 + 2 * FLAT_THREADS]);
        __builtin_nontemporal_store(o3, &out4[t0 + 3 * FLAT_THREADS]);
    }
#undef FLIP1
}

extern "C" void kernel_launch(void* const* d_in, const int* in_sizes, int n_in,
                              void* d_out, int out_size, void* d_ws, size_t ws_size,
                              hipStream_t stream) {
    const float* spins  = (const float*)d_in[0];
    const int*   labels = (const int*)d_in[1];
    const float* coins  = (const float*)d_in[2];
    float*       out    = (float*)d_out;

    // workspace layout (~5.1 MB total)
    char* ws = (char*)d_ws;
    int*      first_idx  = (int*)ws;                                   // 1 MB
    unsigned* bitmap     = (unsigned*)(ws + (1u << 20));               // 2 MB
    int*      wordPrefix = (int*)(ws + 3u * (1u << 20));               // 2 MB
    int*      chunkSums  = (int*)(ws + 5u * (1u << 20));               // 8 KB
    unsigned* seen       = (unsigned*)(ws + 5u*(1u<<20) + (1u<<14));   // 32 KB
    unsigned* flipbits   = (unsigned*)(ws + 5u*(1u<<20) + (1u<<14) + (1u<<15)); // 32 KB

    k_init<<<N_LABELS / 256, 256, 0, stream>>>(first_idx);
    k_seed_blind<<<SEED_BLOCKS + ZERO_BLOCKS, SEED_TPB, 0, stream>>>(
        (const int4*)labels, first_idx, (uint4*)bitmap);
    k_seen<<<N_LABELS / 256, 256, 0, stream>>>(first_idx, seen);
    k_first_flat<<<FLAT_BLOCKS, FLAT_TPB, 0, stream>>>((const int4*)labels, first_idx, seen);
    k_scatter<<<N_LABELS / 256, 256, 0, stream>>>(first_idx, bitmap);
    k_chunk_sums<<<NCHUNKS, WPC, 0, stream>>>(bitmap, chunkSums);
    k_scan<<<1, 1024, 0, stream>>>(chunkSums, NCHUNKS);
    k_word_prefix<<<NCHUNKS, WPC, 0, stream>>>(bitmap, chunkSums, wordPrefix);
    k_rank_flip<<<N_LABELS / 256, 256, 0, stream>>>(first_idx, bitmap, wordPrefix, coins, flipbits);
    k_out<<<FLAT_BLOCKS, FLAT_TPB, 0, stream>>>((const int4*)labels, (const float*)spins,
                                                flipbits, (float*)out);
}